// Round 5
// baseline (2240.899 us; speedup 1.0000x reference)
//
#include <hip/hip_runtime.h>
#include <math.h>

#define BB 8
#define S 256
#define CIN 3
#define W64 64
#define MODES 32
#define PP 34     // MODES + BW - 1
#define KPAD 36   // padded leading dim for Dt

__device__ __forceinline__ float gelu_f(float x){
    return 0.5f * x * (1.0f + erff(x * 0.7071067811865476f));
}

// Dt[h*36 + k] = DCT[k, h]  (orthonormal DCT-II), k < 34, zero-padded to 36
__global__ void k_init_dt(float* __restrict__ dt){
    int tid = blockIdx.x * 256 + threadIdx.x;
    if (tid >= S * KPAD) return;
    int h = tid / KPAD, k = tid % KPAD;
    double v = 0.0;
    if (k < PP) {
        v = sqrt(2.0 / (double)S) * cos(3.14159265358979323846 * (h + 0.5) * k / (double)S);
        if (k == 0) v *= 0.70710678118654752440;
    }
    dt[tid] = (float)v;
}

// x (B,S,S,3) -> h channels 0..2 (channels-last h: (B,S,S,64))
__global__ void k_copy_x(const float* __restrict__ x, float* __restrict__ h){
    int e = blockIdx.x * 256 + threadIdx.x;
    if (e >= BB * S * S * CIN) return;
    int px = e / CIN, c = e % CIN;
    h[(size_t)px * W64 + c] = x[e];
}

// tmp1[b][k][w][c] = sum_h Dt[h][k] * src[b][h][w][c]   (k < 34)
template<int C>
__global__ void k_fwd1(const float* __restrict__ src, float* __restrict__ tmp1,
                       const float* __restrict__ dt){
    int b = blockIdx.y;
    int idx = blockIdx.x * 256 + threadIdx.x;   // flat (w, c)
    if (idx >= S * C) return;
    float acc[PP];
    #pragma unroll
    for (int k = 0; k < PP; k++) acc[k] = 0.f;
    const float* sp = src + (size_t)b * S * S * C + idx;
    for (int hh = 0; hh < S; hh++){
        float v = sp[(size_t)hh * S * C];
        const float* dr = dt + hh * KPAD;
        #pragma unroll
        for (int k = 0; k < PP; k++) acc[k] = fmaf(dr[k], v, acc[k]);
    }
    float* op = tmp1 + (size_t)b * PP * S * C + idx;
    #pragma unroll
    for (int k = 0; k < PP; k++) op[(size_t)k * S * C] = acc[k];
}

// bp[b][k][l][c] = sum_w Dt[w][l] * tmp1[b][k][w][c]   (C=3 path, tiny)
__global__ void k_fwd2_3(const float* __restrict__ tmp1, float* __restrict__ bp,
                         const float* __restrict__ dt){
    const int C = 3;
    int b = blockIdx.y;
    int idx = blockIdx.x * 256 + threadIdx.x;   // flat (k, c)
    if (idx >= PP * C) return;
    int k = idx / C, c = idx % C;
    float acc[PP];
    #pragma unroll
    for (int l = 0; l < PP; l++) acc[l] = 0.f;
    const float* sp = tmp1 + ((size_t)b * PP + k) * S * C + c;
    for (int w = 0; w < S; w++){
        float v = sp[(size_t)w * C];
        const float* dr = dt + w * KPAD;
        #pragma unroll
        for (int l = 0; l < PP; l++) acc[l] = fmaf(dr[l], v, acc[l]);
    }
    float* op = bp + ((size_t)b * PP + k) * PP * C + c;
    #pragma unroll
    for (int l = 0; l < PP; l++) op[(size_t)l * C] = acc[l];
}

// C=64: block = (k, b), 4 waves each own a 64-wide w-segment, LDS reduce.
// (old version had 72 blocks / 1 wave per SIMD -> load-latency-bound)
__global__ __launch_bounds__(256, 4) void k_fwd2_64(
        const float* __restrict__ tmp1, float* __restrict__ bp,
        const float* __restrict__ dt){
    const int C = 64;
    __shared__ float red[4 * PP * 66];   // 35.9 KB
    int k = blockIdx.x, b = blockIdx.y;
    int t = threadIdx.x;
    int c = t & 63;
    int ws = __builtin_amdgcn_readfirstlane(t >> 6);
    float acc[PP];
    #pragma unroll
    for (int l = 0; l < PP; l++) acc[l] = 0.f;
    const float* sp = tmp1 + ((size_t)b * PP + k) * S * C + c;
    for (int w = ws * 64; w < ws * 64 + 64; w++){
        float v = sp[(size_t)w * C];
        const float* dr = dt + w * KPAD;
        #pragma unroll
        for (int l = 0; l < PP; l++) acc[l] = fmaf(dr[l], v, acc[l]);
    }
    #pragma unroll
    for (int l = 0; l < PP; l++) red[(ws * PP + l) * 66 + c] = acc[l];
    __syncthreads();
    float* op = bp + ((size_t)b * PP + k) * PP * C;
    for (int e = t; e < PP * C; e += 256){
        int l = e >> 6, cc = e & 63;
        op[e] = red[(0 * PP + l) * 66 + cc] + red[(1 * PP + l) * 66 + cc]
              + red[(2 * PP + l) * 66 + cc] + red[(3 * PP + l) * 66 + cc];
    }
}

// xp[i][kl][b] = bp[b][k+i_][l+j_][c],  i = c*9 + i_*3 + j_, kl = k*32 + l
template<int C, int CC>
__global__ void k_xp_gather(const float* __restrict__ bp, float* __restrict__ xp){
    __shared__ float lds[8 * 3 * PP * (CC + 1)];
    int k  = blockIdx.x;           // 0..31
    int c0 = blockIdx.y * CC;
    int t  = threadIdx.x;
    const int TOT = 8 * 3 * PP * CC;
    for (int e = t; e < TOT; e += 256){
        int b   = e / (3 * PP * CC);
        int r   = e % (3 * PP * CC);
        int row = r / (PP * CC);
        int r2  = r % (PP * CC);
        int l   = r2 / CC;
        int c   = r2 % CC;
        lds[((b * 3 + row) * PP + l) * (CC + 1) + c] =
            bp[(((size_t)b * PP + (k + row)) * PP + l) * C + c0 + c];
    }
    __syncthreads();
    int l = t >> 3;   // 0..31
    int b = t & 7;
    for (int c = 0; c < CC; c++){
        #pragma unroll
        for (int ij = 0; ij < 9; ij++){
            int i_ = ij / 3, j_ = ij % 3;
            int i  = (c0 + c) * 9 + ij;
            float v = lds[((b * 3 + i_) * PP + (l + j_)) * (CC + 1) + c];
            xp[((size_t)i * 1024 + k * 32 + l) * 8 + b] = v;
        }
    }
}

// part[ns][b][o][kl] = sum_{i in slice ns} xp[i][kl][b] * w[i][o][kl]
template<int ITOT, int O>
__global__ void k_om(const float* __restrict__ xp, const float* __restrict__ w,
                     float* __restrict__ part){
    int bx  = blockIdx.x;
    int klt = bx & 31;
    int ot  = (bx >> 5) & 7;
    int ns  = bx >> 8;              // 0..2
    const int ILEN = ITOT / 3;
    int t  = threadIdx.x;
    int kl = klt * 32 + (t & 31);
    int o  = ot * 8 + (t >> 5);
    if (o >= O) return;
    float a0=0,a1=0,a2=0,a3=0,a4=0,a5=0,a6=0,a7=0;
    const float* xpp = xp + ((size_t)(ns * ILEN) * 1024 + kl) * 8;
    const float* wp  = w + ((size_t)(ns * ILEN) * O + o) * 1024 + kl;
    #pragma unroll 4
    for (int i = 0; i < ILEN; i++){
        float4 xa = *(const float4*)(xpp + (size_t)i * 8192);
        float4 xb = *(const float4*)(xpp + (size_t)i * 8192 + 4);
        float wv  = wp[(size_t)i * O * 1024];
        a0 = fmaf(xa.x, wv, a0); a1 = fmaf(xa.y, wv, a1);
        a2 = fmaf(xa.z, wv, a2); a3 = fmaf(xa.w, wv, a3);
        a4 = fmaf(xb.x, wv, a4); a5 = fmaf(xb.y, wv, a5);
        a6 = fmaf(xb.z, wv, a6); a7 = fmaf(xb.w, wv, a7);
    }
    float* pp = part + (size_t)ns * 8 * 64 * 1024;
    pp[((size_t)0 * 64 + o) * 1024 + kl] = a0;
    pp[((size_t)1 * 64 + o) * 1024 + kl] = a1;
    pp[((size_t)2 * 64 + o) * 1024 + kl] = a2;
    pp[((size_t)3 * 64 + o) * 1024 + kl] = a3;
    pp[((size_t)4 * 64 + o) * 1024 + kl] = a4;
    pp[((size_t)5 * 64 + o) * 1024 + kl] = a5;
    pp[((size_t)6 * 64 + o) * 1024 + kl] = a6;
    pp[((size_t)7 * 64 + o) * 1024 + kl] = a7;
}

// t2[b][k][w][o] = sum_l Dt[w][l] * om[b][o][k*32+l]; om = sum of 3 part slices
// (k_om_reduce folded into the staging loop)
template<int O>
__global__ void k_inv1(const float* __restrict__ part, float* __restrict__ t2,
                       const float* __restrict__ dt){
    __shared__ float oms[32 * 65];
    const int N = 8 * 64 * 1024;
    int wc = blockIdx.x, k = blockIdx.y, b = blockIdx.z;
    int t = threadIdx.x;
    for (int e = t; e < 2048; e += 256){
        int o_ = e >> 5, l = e & 31;
        int idx = ((b * 64 + o_) << 10) + k * 32 + l;
        oms[l * 65 + o_] = part[idx] + part[N + idx] + part[2 * N + idx];
    }
    __syncthreads();
    int o  = t & 63;
    int wg = __builtin_amdgcn_readfirstlane(t >> 6);
    int wbase = wc * 32 + wg * 8;
    float acc[8];
    #pragma unroll
    for (int wj = 0; wj < 8; wj++) acc[wj] = 0.f;
    for (int l = 0; l < 32; l++){
        float ov = oms[l * 65 + o];
        #pragma unroll
        for (int wj = 0; wj < 8; wj++)
            acc[wj] = fmaf(dt[(wbase + wj) * KPAD + l], ov, acc[wj]);
    }
    if (o < O){
        #pragma unroll
        for (int wj = 0; wj < 8; wj++)
            t2[(((size_t)b * 32 + k) * S + wbase + wj) * 64 + o] = acc[wj];
    }
}

// CONV:  h[b][hh][w][o] = h + gelu( conv1x1(h)[o] + pb[o] + sum_k Dt[hh][k]*t2[b][k][w][o] )
// !CONV: h[b][hh][w][3+o] = gelu( sum_k Dt[hh][k]*t2[b][k][w][o] )   (o < 61)
// LDS = 32KB only (t2s; pws overlays after DCT) -> 4 blocks/CU.
// Conv h-operand is a per-wave broadcast: read DIRECTLY from global (L1/L2-hot).
// wdiv is intentionally NOT readfirstlane'd so the address stays divergent-typed
// (VMEM broadcast) -- a provably-uniform address would scalarize onto the
// scalar pipe and serialize (R2 regression).
template<bool CONV>
__global__ __launch_bounds__(256, 4) void k_fused(
        const float* __restrict__ t2, float* __restrict__ h,
        const float* __restrict__ pw, const float* __restrict__ pb,
        const float* __restrict__ dt){
    __shared__ float smem[8192 + 32];
    float* t2s = smem;        // [32k * 4w][64 o]
    float* pws = smem;        // [64 i][65] = pw^T, overlays t2s after DCT
    int ht = blockIdx.x, wt = blockIdx.y, b = blockIdx.z;
    int t = threadIdx.x;
    int o = t & 63;
    int wave = __builtin_amdgcn_readfirstlane(t >> 6);
    int wdiv = (int)(threadIdx.x >> 6);        // divergent-typed wave id
    int w0 = wt * 4;
    int hh0 = ht * 32 + wave * 8;

    for (int e4 = t; e4 < 2048; e4 += 256){
        int k = e4 >> 6, r4 = e4 & 63;
        ((float4*)t2s)[e4] =
            *(const float4*)(t2 + ((size_t)b * 32 + k) * S * 64 + (size_t)w0 * 64 + r4 * 4);
    }
    __syncthreads();

    float acc[8][4];
    #pragma unroll
    for (int hj = 0; hj < 8; hj++)
        #pragma unroll
        for (int wj = 0; wj < 4; wj++) acc[hj][wj] = 0.f;

    // inverse-DCT stage 2 (reads t2s)
    for (int k = 0; k < 32; k++){
        float tv0 = t2s[(k*4+0)*64 + o];
        float tv1 = t2s[(k*4+1)*64 + o];
        float tv2 = t2s[(k*4+2)*64 + o];
        float tv3 = t2s[(k*4+3)*64 + o];
        #pragma unroll
        for (int hj = 0; hj < 8; hj++){
            float d = dt[(hh0 + hj) * KPAD + k];   // wave-uniform constant table
            acc[hj][0] = fmaf(d, tv0, acc[hj][0]);
            acc[hj][1] = fmaf(d, tv1, acc[hj][1]);
            acc[hj][2] = fmaf(d, tv2, acc[hj][2]);
            acc[hj][3] = fmaf(d, tv3, acc[hj][3]);
        }
    }

    if (CONV){
        __syncthreads();                 // all waves done with t2s
        for (int e = t; e < 4096; e += 256){
            pws[(e & 63) * 65 + (e >> 6)] = pw[e];   // e = o*64+i -> pws[i][o]
        }
        __syncthreads();

        const float* hwave = h + (((size_t)b * S + ht * 32 + wdiv * 8) * S + w0) * 64;
        #pragma unroll 1
        for (int i4 = 0; i4 < 16; i4++){
            float w0v = pws[(i4*4+0) * 65 + o];
            float w1v = pws[(i4*4+1) * 65 + o];
            float w2v = pws[(i4*4+2) * 65 + o];
            float w3v = pws[(i4*4+3) * 65 + o];
            #pragma unroll 2
            for (int hj = 0; hj < 8; hj++){
                const float* hrow = hwave + (size_t)hj * S * 64 + i4 * 4;
                #pragma unroll
                for (int wj = 0; wj < 4; wj++){
                    float4 hq = *(const float4*)(hrow + wj * 64);   // wave broadcast
                    float a = acc[hj][wj];
                    a = fmaf(hq.x, w0v, a);
                    a = fmaf(hq.y, w1v, a);
                    a = fmaf(hq.z, w2v, a);
                    a = fmaf(hq.w, w3v, a);
                    acc[hj][wj] = a;
                }
            }
        }

        float pbv = pb[o];
        #pragma unroll
        for (int hj = 0; hj < 8; hj++){
            #pragma unroll
            for (int wj = 0; wj < 4; wj++){
                size_t pix = ((size_t)b * S + ht * 32 + wdiv * 8 + hj) * S + w0 + wj;
                float hval = h[pix * 64 + o];        // residual, L2-hot
                h[pix * 64 + o] = hval + gelu_f(acc[hj][wj] + pbv);
            }
        }
    } else {
        if (o < 61){
            #pragma unroll
            for (int hj = 0; hj < 8; hj++){
                #pragma unroll
                for (int wj = 0; wj < 4; wj++){
                    size_t pix = ((size_t)b * S + hh0 + hj) * S + w0 + wj;
                    h[pix * 64 + 3 + o] = gelu_f(acc[hj][wj]);
                }
            }
        }
    }
}

// out[px] = gelu(h_px @ fc1 + b1) @ fc2 + b2
__global__ void k_mlp(const float* __restrict__ h, const float* __restrict__ fc1w,
                      const float* __restrict__ fc1b, const float* __restrict__ fc2w,
                      const float* __restrict__ fc2b, float* __restrict__ out){
    __shared__ float hs[64 * 65];
    __shared__ float red[256];
    size_t base = (size_t)blockIdx.x * 64;   // first pixel of this block
    int t = threadIdx.x;
    const float* hrow = h + base * 64;
    for (int e = t; e < 4096; e += 256){
        int p = e >> 6, i = e & 63;
        hs[p * 65 + i] = hrow[e];
    }
    __syncthreads();
    int p = t & 63;
    int q = __builtin_amdgcn_readfirstlane(t >> 6);   // wave-uniform j-chunk
    float acc[32];
    const float* b1 = fc1b + q * 32;
    #pragma unroll
    for (int j = 0; j < 32; j++) acc[j] = b1[j];
    for (int i = 0; i < 64; i++){
        float hv = hs[p * 65 + i];
        const float* f1 = fc1w + i * 128 + q * 32;    // wave-uniform -> s_load
        #pragma unroll
        for (int j = 0; j < 32; j++) acc[j] = fmaf(hv, f1[j], acc[j]);
    }
    const float* f2 = fc2w + q * 32;
    float y = 0.f;
    #pragma unroll
    for (int j = 0; j < 32; j++) y = fmaf(gelu_f(acc[j]), f2[j], y);
    red[t] = y;
    __syncthreads();
    if (t < 64){
        out[base + t] = red[t] + red[64 + t] + red[128 + t] + red[192 + t] + fc2b[0];
    }
}

extern "C" void kernel_launch(void* const* d_in, const int* in_sizes, int n_in,
                              void* d_out, int out_size, void* d_ws, size_t ws_size,
                              hipStream_t stream) {
    const float* x    = (const float*)d_in[0];
    const float* wl   = (const float*)d_in[1];
    const float* wc[4] = {(const float*)d_in[2], (const float*)d_in[3],
                          (const float*)d_in[4], (const float*)d_in[5]};
    const float* pw[4] = {(const float*)d_in[6], (const float*)d_in[8],
                          (const float*)d_in[10], (const float*)d_in[12]};
    const float* pb[4] = {(const float*)d_in[7], (const float*)d_in[9],
                          (const float*)d_in[11], (const float*)d_in[13]};
    const float* fc1w = (const float*)d_in[14];
    const float* fc1b = (const float*)d_in[15];
    const float* fc2w = (const float*)d_in[16];
    const float* fc2b = (const float*)d_in[17];
    float* out = (float*)d_out;

    char* ws = (char*)d_ws;
    size_t off = 0;
    float* dt   = (float*)(ws + off); off += (size_t)S * KPAD * 4;              // 36,864
    float* h    = (float*)(ws + off); off += (size_t)BB * S * S * W64 * 4;      // 134,217,728
    float* tmp1 = (float*)(ws + off); off += (size_t)BB * PP * S * W64 * 4;     // 17,825,792
    float* bp   = (float*)(ws + off); off += (size_t)BB * PP * PP * W64 * 4;    // 2,367,488
    float* xp   = (float*)(ws + off); off += (size_t)576 * 1024 * 8 * 4;        // 18,874,368
    float* part = (float*)(ws + off); off += (size_t)3 * 8 * 64 * 1024 * 4;     // 6,291,456
    float* t2   = (float*)(ws + off); off += (size_t)BB * 32 * S * W64 * 4;     // 16,777,216

    k_init_dt<<<36, 256, 0, stream>>>(dt);
    k_copy_x<<<(BB * S * S * CIN + 255) / 256, 256, 0, stream>>>(x, h);

    // ---- block 0: h[:, :, :, 3:] = gelu(pseudo_spectra(x, wl, 61)) ----
    k_fwd1<3><<<dim3(3, BB), 256, 0, stream>>>(x, tmp1, dt);
    k_fwd2_3<<<dim3(1, BB), 256, 0, stream>>>(tmp1, bp, dt);
    k_xp_gather<3, 3><<<dim3(32, 1), 256, 0, stream>>>(bp, xp);
    k_om<27, 61><<<768, 256, 0, stream>>>(xp, wl, part);
    k_inv1<61><<<dim3(8, 32, BB), 256, 0, stream>>>(part, t2, dt);
    k_fused<false><<<dim3(8, 64, BB), 256, 0, stream>>>(t2, h, nullptr, nullptr, dt);

    // ---- blocks 1..4 ----
    for (int blk = 0; blk < 4; blk++){
        k_fwd1<64><<<dim3(64, BB), 256, 0, stream>>>(h, tmp1, dt);
        k_fwd2_64<<<dim3(PP, BB), 256, 0, stream>>>(tmp1, bp, dt);
        k_xp_gather<64, 16><<<dim3(32, 4), 256, 0, stream>>>(bp, xp);
        k_om<576, 64><<<768, 256, 0, stream>>>(xp, wc[blk], part);
        k_inv1<64><<<dim3(8, 32, BB), 256, 0, stream>>>(part, t2, dt);
        k_fused<true><<<dim3(8, 64, BB), 256, 0, stream>>>(t2, h, pw[blk], pb[blk], dt);
    }

    // ---- final MLP (T_fwd(T_inv2(.)) is identity for the orthonormal DCT) ----
    k_mlp<<<dim3(BB * S * S / 64), 256, 0, stream>>>(h, fc1w, fc1b, fc2w, fc2b, out);
}

// Round 6
// 1829.815 us; speedup vs baseline: 1.2247x; 1.2247x over previous
//
#include <hip/hip_runtime.h>
#include <math.h>

#define BB 8
#define S 256
#define CIN 3
#define W64 64
#define MODES 32
#define PP 34     // MODES + BW - 1
#define KPAD 36   // padded leading dim for Dt

__device__ __forceinline__ float gelu_f(float x){
    return 0.5f * x * (1.0f + erff(x * 0.7071067811865476f));
}

// Dt[h*36 + k] = DCT[k, h]  (orthonormal DCT-II), k < 34, zero-padded to 36
__global__ void k_init_dt(float* __restrict__ dt){
    int tid = blockIdx.x * 256 + threadIdx.x;
    if (tid >= S * KPAD) return;
    int h = tid / KPAD, k = tid % KPAD;
    double v = 0.0;
    if (k < PP) {
        v = sqrt(2.0 / (double)S) * cos(3.14159265358979323846 * (h + 0.5) * k / (double)S);
        if (k == 0) v *= 0.70710678118654752440;
    }
    dt[tid] = (float)v;
}

// x (B,S,S,3) -> h channels 0..2 (channels-last h: (B,S,S,64))
__global__ void k_copy_x(const float* __restrict__ x, float* __restrict__ h){
    int e = blockIdx.x * 256 + threadIdx.x;
    if (e >= BB * S * S * CIN) return;
    int px = e / CIN, c = e % CIN;
    h[(size_t)px * W64 + c] = x[e];
}

// tmp1[b][k][w][c] = sum_h Dt[h][k] * src[b][h][w][c]   (k < 34)
template<int C>
__global__ void k_fwd1(const float* __restrict__ src, float* __restrict__ tmp1,
                       const float* __restrict__ dt){
    int b = blockIdx.y;
    int idx = blockIdx.x * 256 + threadIdx.x;   // flat (w, c)
    if (idx >= S * C) return;
    float acc[PP];
    #pragma unroll
    for (int k = 0; k < PP; k++) acc[k] = 0.f;
    const float* sp = src + (size_t)b * S * S * C + idx;
    for (int hh = 0; hh < S; hh++){
        float v = sp[(size_t)hh * S * C];
        const float* dr = dt + hh * KPAD;
        #pragma unroll
        for (int k = 0; k < PP; k++) acc[k] = fmaf(dr[k], v, acc[k]);
    }
    float* op = tmp1 + (size_t)b * PP * S * C + idx;
    #pragma unroll
    for (int k = 0; k < PP; k++) op[(size_t)k * S * C] = acc[k];
}

// bp[b][k][l][c] = sum_w Dt[w][l] * tmp1[b][k][w][c]   (C=3 path, tiny)
__global__ void k_fwd2_3(const float* __restrict__ tmp1, float* __restrict__ bp,
                         const float* __restrict__ dt){
    const int C = 3;
    int b = blockIdx.y;
    int idx = blockIdx.x * 256 + threadIdx.x;   // flat (k, c)
    if (idx >= PP * C) return;
    int k = idx / C, c = idx % C;
    float acc[PP];
    #pragma unroll
    for (int l = 0; l < PP; l++) acc[l] = 0.f;
    const float* sp = tmp1 + ((size_t)b * PP + k) * S * C + c;
    for (int w = 0; w < S; w++){
        float v = sp[(size_t)w * C];
        const float* dr = dt + w * KPAD;
        #pragma unroll
        for (int l = 0; l < PP; l++) acc[l] = fmaf(dr[l], v, acc[l]);
    }
    float* op = bp + ((size_t)b * PP + k) * PP * C + c;
    #pragma unroll
    for (int l = 0; l < PP; l++) op[(size_t)l * C] = acc[l];
}

// C=64: block = (k, b), 4 waves each own a 64-wide w-segment, LDS reduce.
__global__ __launch_bounds__(256, 4) void k_fwd2_64(
        const float* __restrict__ tmp1, float* __restrict__ bp,
        const float* __restrict__ dt){
    const int C = 64;
    __shared__ float red[4 * PP * 66];   // 35.9 KB
    int k = blockIdx.x, b = blockIdx.y;
    int t = threadIdx.x;
    int c = t & 63;
    int ws = __builtin_amdgcn_readfirstlane(t >> 6);
    float acc[PP];
    #pragma unroll
    for (int l = 0; l < PP; l++) acc[l] = 0.f;
    const float* sp = tmp1 + ((size_t)b * PP + k) * S * C + c;
    for (int w = ws * 64; w < ws * 64 + 64; w++){
        float v = sp[(size_t)w * C];
        const float* dr = dt + w * KPAD;
        #pragma unroll
        for (int l = 0; l < PP; l++) acc[l] = fmaf(dr[l], v, acc[l]);
    }
    #pragma unroll
    for (int l = 0; l < PP; l++) red[(ws * PP + l) * 66 + c] = acc[l];
    __syncthreads();
    float* op = bp + ((size_t)b * PP + k) * PP * C;
    for (int e = t; e < PP * C; e += 256){
        int l = e >> 6, cc = e & 63;
        op[e] = red[(0 * PP + l) * 66 + cc] + red[(1 * PP + l) * 66 + cc]
              + red[(2 * PP + l) * 66 + cc] + red[(3 * PP + l) * 66 + cc];
    }
}

// xp[i][kl][b] = bp[b][k+i_][l+j_][c],  i = c*9 + i_*3 + j_, kl = k*32 + l
template<int C, int CC>
__global__ void k_xp_gather(const float* __restrict__ bp, float* __restrict__ xp){
    __shared__ float lds[8 * 3 * PP * (CC + 1)];
    int k  = blockIdx.x;           // 0..31
    int c0 = blockIdx.y * CC;
    int t  = threadIdx.x;
    const int TOT = 8 * 3 * PP * CC;
    for (int e = t; e < TOT; e += 256){
        int b   = e / (3 * PP * CC);
        int r   = e % (3 * PP * CC);
        int row = r / (PP * CC);
        int r2  = r % (PP * CC);
        int l   = r2 / CC;
        int c   = r2 % CC;
        lds[((b * 3 + row) * PP + l) * (CC + 1) + c] =
            bp[(((size_t)b * PP + (k + row)) * PP + l) * C + c0 + c];
    }
    __syncthreads();
    int l = t >> 3;   // 0..31
    int b = t & 7;
    for (int c = 0; c < CC; c++){
        #pragma unroll
        for (int ij = 0; ij < 9; ij++){
            int i_ = ij / 3, j_ = ij % 3;
            int i  = (c0 + c) * 9 + ij;
            float v = lds[((b * 3 + i_) * PP + (l + j_)) * (CC + 1) + c];
            xp[((size_t)i * 1024 + k * 32 + l) * 8 + b] = v;
        }
    }
}

// part[ns][b][o][kl] = sum_{i in slice ns} xp[i][kl][b] * w[i][o][kl]
template<int ITOT, int O>
__global__ void k_om(const float* __restrict__ xp, const float* __restrict__ w,
                     float* __restrict__ part){
    int bx  = blockIdx.x;
    int klt = bx & 31;
    int ot  = (bx >> 5) & 7;
    int ns  = bx >> 8;              // 0..2
    const int ILEN = ITOT / 3;
    int t  = threadIdx.x;
    int kl = klt * 32 + (t & 31);
    int o  = ot * 8 + (t >> 5);
    if (o >= O) return;
    float a0=0,a1=0,a2=0,a3=0,a4=0,a5=0,a6=0,a7=0;
    const float* xpp = xp + ((size_t)(ns * ILEN) * 1024 + kl) * 8;
    const float* wp  = w + ((size_t)(ns * ILEN) * O + o) * 1024 + kl;
    #pragma unroll 4
    for (int i = 0; i < ILEN; i++){
        float4 xa = *(const float4*)(xpp + (size_t)i * 8192);
        float4 xb = *(const float4*)(xpp + (size_t)i * 8192 + 4);
        float wv  = wp[(size_t)i * O * 1024];
        a0 = fmaf(xa.x, wv, a0); a1 = fmaf(xa.y, wv, a1);
        a2 = fmaf(xa.z, wv, a2); a3 = fmaf(xa.w, wv, a3);
        a4 = fmaf(xb.x, wv, a4); a5 = fmaf(xb.y, wv, a5);
        a6 = fmaf(xb.z, wv, a6); a7 = fmaf(xb.w, wv, a7);
    }
    float* pp = part + (size_t)ns * 8 * 64 * 1024;
    pp[((size_t)0 * 64 + o) * 1024 + kl] = a0;
    pp[((size_t)1 * 64 + o) * 1024 + kl] = a1;
    pp[((size_t)2 * 64 + o) * 1024 + kl] = a2;
    pp[((size_t)3 * 64 + o) * 1024 + kl] = a3;
    pp[((size_t)4 * 64 + o) * 1024 + kl] = a4;
    pp[((size_t)5 * 64 + o) * 1024 + kl] = a5;
    pp[((size_t)6 * 64 + o) * 1024 + kl] = a6;
    pp[((size_t)7 * 64 + o) * 1024 + kl] = a7;
}

// t2[b][k][w][o] = sum_l Dt[w][l] * om[b][o][k*32+l]; om = sum of 3 part slices
template<int O>
__global__ void k_inv1(const float* __restrict__ part, float* __restrict__ t2,
                       const float* __restrict__ dt){
    __shared__ float oms[32 * 65];
    const int N = 8 * 64 * 1024;
    int wc = blockIdx.x, k = blockIdx.y, b = blockIdx.z;
    int t = threadIdx.x;
    for (int e = t; e < 2048; e += 256){
        int o_ = e >> 5, l = e & 31;
        int idx = ((b * 64 + o_) << 10) + k * 32 + l;
        oms[l * 65 + o_] = part[idx] + part[N + idx] + part[2 * N + idx];
    }
    __syncthreads();
    int o  = t & 63;
    int wg = __builtin_amdgcn_readfirstlane(t >> 6);
    int wbase = wc * 32 + wg * 8;
    float acc[8];
    #pragma unroll
    for (int wj = 0; wj < 8; wj++) acc[wj] = 0.f;
    for (int l = 0; l < 32; l++){
        float ov = oms[l * 65 + o];
        #pragma unroll
        for (int wj = 0; wj < 8; wj++)
            acc[wj] = fmaf(dt[(wbase + wj) * KPAD + l], ov, acc[wj]);
    }
    if (o < O){
        #pragma unroll
        for (int wj = 0; wj < 8; wj++)
            t2[(((size_t)b * 32 + k) * S + wbase + wj) * 64 + o] = acc[wj];
    }
}

// CONV:  h[b][hh][w][o] = hs + gelu( conv1x1(hs)[o] + pb[o] + sum_k Dt[hh][k]*t2[b][k][w][o] )
// !CONV: h[b][hh][w][3+o] = gelu( sum_k Dt[hh][k]*t2[b][k][w][o] )   (o < 61)
// Geometry: block = 2 w x 32 hh x 64 o  (R4 was 4w: 64KB LDS -> 2 blocks/CU,
// latency-bound; R5's global-broadcast conv operand regressed -> back to LDS).
// LDS = t2s/pws region (16.9 KB) + hs (16 KB) = 33 KB -> 4 blocks/CU.
// t2 tile is hh-independent; the 8 ht-blocks sharing it stage it L2-hot.
template<bool CONV>
__global__ __launch_bounds__(256, 4) void k_fused(
        const float* __restrict__ t2, float* __restrict__ h,
        const float* __restrict__ pw, const float* __restrict__ pb,
        const float* __restrict__ dt){
    __shared__ float smem[CONV ? (4224 + 4096) : 4096];
    float* t2s = smem;                        // [32 k][2 w][64 o] = 4096 floats
    float* pws = smem;                        // [64 i][66] pw^T, overlays t2s
    float* hs  = smem + (CONV ? 4224 : 0);    // [64 px = 32hh x 2w][64 i]
    int ht = blockIdx.x, wt = blockIdx.y, b = blockIdx.z;
    int t = threadIdx.x;
    int o = t & 63;
    int wave = __builtin_amdgcn_readfirstlane(t >> 6);
    int w0 = wt * 2;
    int hh0 = ht * 32 + wave * 8;

    // stage t2 tile: 32k x 128 contiguous floats each (w0, w0+1 adjacent)
    for (int e4 = t; e4 < 1024; e4 += 256){
        int k = e4 >> 5, r = e4 & 31;
        ((float4*)t2s)[e4] =
            *(const float4*)(t2 + ((size_t)b * 32 + k) * S * 64 + (size_t)w0 * 64 + r * 4);
    }
    if (CONV){
        // stage h tile: 64 px x 64 ch; px = hh_local*2 + wj (256B contiguous/hh)
        const float* hbase = h + (((size_t)b * S + ht * 32) * S + w0) * 64;
        for (int e4 = t; e4 < 1024; e4 += 256){
            int px = e4 >> 4, i4 = e4 & 15;
            ((float4*)hs)[e4] =
                *(const float4*)(hbase + ((size_t)(px >> 1) * S + (px & 1)) * 64 + i4 * 4);
        }
    }
    __syncthreads();

    float acc[8][2];
    #pragma unroll
    for (int hj = 0; hj < 8; hj++){ acc[hj][0] = 0.f; acc[hj][1] = 0.f; }

    // inverse-DCT stage 2 (reads t2s)
    for (int k = 0; k < 32; k++){
        float tv0 = t2s[(k*2+0)*64 + o];
        float tv1 = t2s[(k*2+1)*64 + o];
        #pragma unroll
        for (int hj = 0; hj < 8; hj++){
            float d = dt[(hh0 + hj) * KPAD + k];   // wave-uniform constant table
            acc[hj][0] = fmaf(d, tv0, acc[hj][0]);
            acc[hj][1] = fmaf(d, tv1, acc[hj][1]);
        }
    }

    if (CONV){
        __syncthreads();                 // all waves done with t2s
        for (int e = t; e < 4096; e += 256){
            pws[(e & 63) * 66 + (e >> 6)] = pw[e];   // e = o*64+i -> pws[i][o]
        }
        __syncthreads();

        int pxb = wave * 16;             // first px of this wave (8 hh x 2 w)
        #pragma unroll 1
        for (int i4 = 0; i4 < 16; i4++){
            float w0v = pws[(i4*4+0) * 66 + o];
            float w1v = pws[(i4*4+1) * 66 + o];
            float w2v = pws[(i4*4+2) * 66 + o];
            float w3v = pws[(i4*4+3) * 66 + o];
            #pragma unroll 2
            for (int hj = 0; hj < 8; hj++){
                #pragma unroll
                for (int wj = 0; wj < 2; wj++){
                    float4 hq = *(const float4*)(hs + (pxb + hj*2 + wj) * 64 + i4 * 4);
                    float a = acc[hj][wj];               // hs read = broadcast (free)
                    a = fmaf(hq.x, w0v, a);
                    a = fmaf(hq.y, w1v, a);
                    a = fmaf(hq.z, w2v, a);
                    a = fmaf(hq.w, w3v, a);
                    acc[hj][wj] = a;
                }
            }
        }

        float pbv = pb[o];
        #pragma unroll
        for (int hj = 0; hj < 8; hj++){
            #pragma unroll
            for (int wj = 0; wj < 2; wj++){
                size_t pix = ((size_t)b * S + hh0 + hj) * S + w0 + wj;
                float hval = hs[(pxb + hj*2 + wj) * 64 + o];   // residual from LDS
                h[pix * 64 + o] = hval + gelu_f(acc[hj][wj] + pbv);
            }
        }
    } else {
        if (o < 61){
            #pragma unroll
            for (int hj = 0; hj < 8; hj++){
                #pragma unroll
                for (int wj = 0; wj < 2; wj++){
                    size_t pix = ((size_t)b * S + hh0 + hj) * S + w0 + wj;
                    h[pix * 64 + 3 + o] = gelu_f(acc[hj][wj]);
                }
            }
        }
    }
}

// out[px] = gelu(h_px @ fc1 + b1) @ fc2 + b2
__global__ void k_mlp(const float* __restrict__ h, const float* __restrict__ fc1w,
                      const float* __restrict__ fc1b, const float* __restrict__ fc2w,
                      const float* __restrict__ fc2b, float* __restrict__ out){
    __shared__ float hs[64 * 65];
    __shared__ float red[256];
    size_t base = (size_t)blockIdx.x * 64;   // first pixel of this block
    int t = threadIdx.x;
    const float* hrow = h + base * 64;
    for (int e = t; e < 4096; e += 256){
        int p = e >> 6, i = e & 63;
        hs[p * 65 + i] = hrow[e];
    }
    __syncthreads();
    int p = t & 63;
    int q = __builtin_amdgcn_readfirstlane(t >> 6);   // wave-uniform j-chunk
    float acc[32];
    const float* b1 = fc1b + q * 32;
    #pragma unroll
    for (int j = 0; j < 32; j++) acc[j] = b1[j];
    for (int i = 0; i < 64; i++){
        float hv = hs[p * 65 + i];
        const float* f1 = fc1w + i * 128 + q * 32;    // wave-uniform -> s_load
        #pragma unroll
        for (int j = 0; j < 32; j++) acc[j] = fmaf(hv, f1[j], acc[j]);
    }
    const float* f2 = fc2w + q * 32;
    float y = 0.f;
    #pragma unroll
    for (int j = 0; j < 32; j++) y = fmaf(gelu_f(acc[j]), f2[j], y);
    red[t] = y;
    __syncthreads();
    if (t < 64){
        out[base + t] = red[t] + red[64 + t] + red[128 + t] + red[192 + t] + fc2b[0];
    }
}

extern "C" void kernel_launch(void* const* d_in, const int* in_sizes, int n_in,
                              void* d_out, int out_size, void* d_ws, size_t ws_size,
                              hipStream_t stream) {
    const float* x    = (const float*)d_in[0];
    const float* wl   = (const float*)d_in[1];
    const float* wc[4] = {(const float*)d_in[2], (const float*)d_in[3],
                          (const float*)d_in[4], (const float*)d_in[5]};
    const float* pw[4] = {(const float*)d_in[6], (const float*)d_in[8],
                          (const float*)d_in[10], (const float*)d_in[12]};
    const float* pb[4] = {(const float*)d_in[7], (const float*)d_in[9],
                          (const float*)d_in[11], (const float*)d_in[13]};
    const float* fc1w = (const float*)d_in[14];
    const float* fc1b = (const float*)d_in[15];
    const float* fc2w = (const float*)d_in[16];
    const float* fc2b = (const float*)d_in[17];
    float* out = (float*)d_out;

    char* ws = (char*)d_ws;
    size_t off = 0;
    float* dt   = (float*)(ws + off); off += (size_t)S * KPAD * 4;              // 36,864
    float* h    = (float*)(ws + off); off += (size_t)BB * S * S * W64 * 4;      // 134,217,728
    float* tmp1 = (float*)(ws + off); off += (size_t)BB * PP * S * W64 * 4;     // 17,825,792
    float* bp   = (float*)(ws + off); off += (size_t)BB * PP * PP * W64 * 4;    // 2,367,488
    float* xp   = (float*)(ws + off); off += (size_t)576 * 1024 * 8 * 4;        // 18,874,368
    float* part = (float*)(ws + off); off += (size_t)3 * 8 * 64 * 1024 * 4;     // 6,291,456
    float* t2   = (float*)(ws + off); off += (size_t)BB * 32 * S * W64 * 4;     // 16,777,216

    k_init_dt<<<36, 256, 0, stream>>>(dt);
    k_copy_x<<<(BB * S * S * CIN + 255) / 256, 256, 0, stream>>>(x, h);

    // ---- block 0: h[:, :, :, 3:] = gelu(pseudo_spectra(x, wl, 61)) ----
    k_fwd1<3><<<dim3(3, BB), 256, 0, stream>>>(x, tmp1, dt);
    k_fwd2_3<<<dim3(1, BB), 256, 0, stream>>>(tmp1, bp, dt);
    k_xp_gather<3, 3><<<dim3(32, 1), 256, 0, stream>>>(bp, xp);
    k_om<27, 61><<<768, 256, 0, stream>>>(xp, wl, part);
    k_inv1<61><<<dim3(8, 32, BB), 256, 0, stream>>>(part, t2, dt);
    k_fused<false><<<dim3(8, 128, BB), 256, 0, stream>>>(t2, h, nullptr, nullptr, dt);

    // ---- blocks 1..4 ----
    for (int blk = 0; blk < 4; blk++){
        k_fwd1<64><<<dim3(64, BB), 256, 0, stream>>>(h, tmp1, dt);
        k_fwd2_64<<<dim3(PP, BB), 256, 0, stream>>>(tmp1, bp, dt);
        k_xp_gather<64, 16><<<dim3(32, 4), 256, 0, stream>>>(bp, xp);
        k_om<576, 64><<<768, 256, 0, stream>>>(xp, wc[blk], part);
        k_inv1<64><<<dim3(8, 32, BB), 256, 0, stream>>>(part, t2, dt);
        k_fused<true><<<dim3(8, 128, BB), 256, 0, stream>>>(t2, h, pw[blk], pb[blk], dt);
    }

    // ---- final MLP (T_fwd(T_inv2(.)) is identity for the orthonormal DCT) ----
    k_mlp<<<dim3(BB * S * S / 64), 256, 0, stream>>>(h, fc1w, fc1b, fc2w, fc2b, out);
}

// Round 8
// 1487.730 us; speedup vs baseline: 1.5063x; 1.2299x over previous
//
#include <hip/hip_runtime.h>
#include <math.h>

#define BB 8
#define S 256
#define CIN 3
#define W64 64
#define MODES 32
#define PP 34     // MODES + BW - 1
#define KPAD 36   // padded leading dim for f32 Dt
#define KPB 40    // padded leading dim for bf16 Dt tables (16B-aligned frag loads)

typedef __attribute__((ext_vector_type(8))) short bfrag;    // 8 bf16 raw bits
typedef __attribute__((ext_vector_type(16))) float f32x16;

// fast erf-based gelu: A&S 7.1.26, |erf err| <= 1.5e-7 (libm erff is ~40 insts)
__device__ __forceinline__ float gelu_f(float x){
    float z = fabsf(x) * 0.70710678118654752f;
    float t = 1.0f / (1.0f + 0.3275911f * z);
    float p = ((((1.061405429f * t - 1.453152027f) * t) + 1.421413741f) * t
               - 0.284496736f) * t + 0.254829592f;
    float e = __expf(-z * z);
    float erf = 1.0f - p * t * e;
    erf = copysignf(erf, x);
    return 0.5f * x * (1.0f + erf);
}

// split x into bf16 hi + bf16 lo (round-to-nearest-even), x ~= hi + lo
__device__ __forceinline__ void split_bf(float x, short &hi, short &lo){
    unsigned u = __float_as_uint(x);
    unsigned r = u + 0x7FFFu + ((u >> 16) & 1u);
    hi = (short)(r >> 16);
    float hf = __uint_as_float(r & 0xFFFF0000u);
    float l = x - hf;
    unsigned v = __float_as_uint(l);
    unsigned s2 = v + 0x7FFFu + ((v >> 16) & 1u);
    lo = (short)(s2 >> 16);
}

// dt[h*36+k] = DCT[k,h] f32; dth/dtl[h*40+k] = bf16 hi/lo split
__global__ void k_init_dt(float* __restrict__ dt, short* __restrict__ dth,
                          short* __restrict__ dtl){
    int tid = blockIdx.x * 256 + threadIdx.x;
    if (tid >= S * KPB) return;
    int h = tid / KPB, k = tid % KPB;
    double v = 0.0;
    if (k < PP) {
        v = sqrt(2.0 / (double)S) * cos(3.14159265358979323846 * (h + 0.5) * k / (double)S);
        if (k == 0) v *= 0.70710678118654752440;
    }
    float f = (float)v;
    if (k < KPAD) dt[h * KPAD + k] = f;
    short hi, lo; split_bf(f, hi, lo);
    dth[tid] = hi; dtl[tid] = lo;
}

// split a 64x64 conv weight into bf16 hi/lo (layout preserved: pw[o][i])
__global__ void k_prep_pw(const float* __restrict__ pw, short* __restrict__ pwh,
                          short* __restrict__ pwl){
    int e = blockIdx.x * 256 + threadIdx.x;
    if (e >= 4096) return;
    short hi, lo; split_bf(pw[e], hi, lo);
    pwh[e] = hi; pwl[e] = lo;
}

// x (B,S,S,3) -> h channels 0..2 (channels-last h: (B,S,S,64))
__global__ void k_copy_x(const float* __restrict__ x, float* __restrict__ h){
    int e = blockIdx.x * 256 + threadIdx.x;
    if (e >= BB * S * S * CIN) return;
    int px = e / CIN, c = e % CIN;
    h[(size_t)px * W64 + c] = x[e];
}

// tmp1[b][k][w][c] = sum_h Dt[h][k] * src[b][h][w][c]   (k < 34)
template<int C>
__global__ void k_fwd1(const float* __restrict__ src, float* __restrict__ tmp1,
                       const float* __restrict__ dt){
    int b = blockIdx.y;
    int idx = blockIdx.x * 256 + threadIdx.x;   // flat (w, c)
    if (idx >= S * C) return;
    float acc[PP];
    #pragma unroll
    for (int k = 0; k < PP; k++) acc[k] = 0.f;
    const float* sp = src + (size_t)b * S * S * C + idx;
    for (int hh = 0; hh < S; hh++){
        float v = sp[(size_t)hh * S * C];
        const float* dr = dt + hh * KPAD;
        #pragma unroll
        for (int k = 0; k < PP; k++) acc[k] = fmaf(dr[k], v, acc[k]);
    }
    float* op = tmp1 + (size_t)b * PP * S * C + idx;
    #pragma unroll
    for (int k = 0; k < PP; k++) op[(size_t)k * S * C] = acc[k];
}

// bp[b][k][l][c] = sum_w Dt[w][l] * tmp1[b][k][w][c]   (C=3 path, tiny)
__global__ void k_fwd2_3(const float* __restrict__ tmp1, float* __restrict__ bp,
                         const float* __restrict__ dt){
    const int C = 3;
    int b = blockIdx.y;
    int idx = blockIdx.x * 256 + threadIdx.x;   // flat (k, c)
    if (idx >= PP * C) return;
    int k = idx / C, c = idx % C;
    float acc[PP];
    #pragma unroll
    for (int l = 0; l < PP; l++) acc[l] = 0.f;
    const float* sp = tmp1 + ((size_t)b * PP + k) * S * C + c;
    for (int w = 0; w < S; w++){
        float v = sp[(size_t)w * C];
        const float* dr = dt + w * KPAD;
        #pragma unroll
        for (int l = 0; l < PP; l++) acc[l] = fmaf(dr[l], v, acc[l]);
    }
    float* op = bp + ((size_t)b * PP + k) * PP * C + c;
    #pragma unroll
    for (int l = 0; l < PP; l++) op[(size_t)l * C] = acc[l];
}

// C=64: block = (k, b), 4 waves each own a 64-wide w-segment, LDS reduce.
__global__ __launch_bounds__(256, 4) void k_fwd2_64(
        const float* __restrict__ tmp1, float* __restrict__ bp,
        const float* __restrict__ dt){
    const int C = 64;
    __shared__ float red[4 * PP * 66];   // 35.9 KB
    int k = blockIdx.x, b = blockIdx.y;
    int t = threadIdx.x;
    int c = t & 63;
    int ws = __builtin_amdgcn_readfirstlane(t >> 6);
    float acc[PP];
    #pragma unroll
    for (int l = 0; l < PP; l++) acc[l] = 0.f;
    const float* sp = tmp1 + ((size_t)b * PP + k) * S * C + c;
    for (int w = ws * 64; w < ws * 64 + 64; w++){
        float v = sp[(size_t)w * C];
        const float* dr = dt + w * KPAD;
        #pragma unroll
        for (int l = 0; l < PP; l++) acc[l] = fmaf(dr[l], v, acc[l]);
    }
    #pragma unroll
    for (int l = 0; l < PP; l++) red[(ws * PP + l) * 66 + c] = acc[l];
    __syncthreads();
    float* op = bp + ((size_t)b * PP + k) * PP * C;
    for (int e = t; e < PP * C; e += 256){
        int l = e >> 6, cc = e & 63;
        op[e] = red[(0 * PP + l) * 66 + cc] + red[(1 * PP + l) * 66 + cc]
              + red[(2 * PP + l) * 66 + cc] + red[(3 * PP + l) * 66 + cc];
    }
}

// xp[i][kl][b] = bp[b][k+i_][l+j_][c],  i = c*9 + i_*3 + j_, kl = k*32 + l
template<int C, int CC>
__global__ void k_xp_gather(const float* __restrict__ bp, float* __restrict__ xp){
    __shared__ float lds[8 * 3 * PP * (CC + 1)];
    int k  = blockIdx.x;           // 0..31
    int c0 = blockIdx.y * CC;
    int t  = threadIdx.x;
    const int TOT = 8 * 3 * PP * CC;
    for (int e = t; e < TOT; e += 256){
        int b   = e / (3 * PP * CC);
        int r   = e % (3 * PP * CC);
        int row = r / (PP * CC);
        int r2  = r % (PP * CC);
        int l   = r2 / CC;
        int c   = r2 % CC;
        lds[((b * 3 + row) * PP + l) * (CC + 1) + c] =
            bp[(((size_t)b * PP + (k + row)) * PP + l) * C + c0 + c];
    }
    __syncthreads();
    int l = t >> 3;   // 0..31
    int b = t & 7;
    for (int c = 0; c < CC; c++){
        #pragma unroll
        for (int ij = 0; ij < 9; ij++){
            int i_ = ij / 3, j_ = ij % 3;
            int i  = (c0 + c) * 9 + ij;
            float v = lds[((b * 3 + i_) * PP + (l + j_)) * (CC + 1) + c];
            xp[((size_t)i * 1024 + k * 32 + l) * 8 + b] = v;
        }
    }
}

// part[ns][b][o][kl] = sum_{i in slice ns} xp[i][kl][b] * w[i][o][kl]
template<int ITOT, int O>
__global__ void k_om(const float* __restrict__ xp, const float* __restrict__ w,
                     float* __restrict__ part){
    int bx  = blockIdx.x;
    int klt = bx & 31;
    int ot  = (bx >> 5) & 7;
    int ns  = bx >> 8;              // 0..2
    const int ILEN = ITOT / 3;
    int t  = threadIdx.x;
    int kl = klt * 32 + (t & 31);
    int o  = ot * 8 + (t >> 5);
    if (o >= O) return;
    float a0=0,a1=0,a2=0,a3=0,a4=0,a5=0,a6=0,a7=0;
    const float* xpp = xp + ((size_t)(ns * ILEN) * 1024 + kl) * 8;
    const float* wp  = w + ((size_t)(ns * ILEN) * O + o) * 1024 + kl;
    #pragma unroll 4
    for (int i = 0; i < ILEN; i++){
        float4 xa = *(const float4*)(xpp + (size_t)i * 8192);
        float4 xb = *(const float4*)(xpp + (size_t)i * 8192 + 4);
        float wv  = wp[(size_t)i * O * 1024];
        a0 = fmaf(xa.x, wv, a0); a1 = fmaf(xa.y, wv, a1);
        a2 = fmaf(xa.z, wv, a2); a3 = fmaf(xa.w, wv, a3);
        a4 = fmaf(xb.x, wv, a4); a5 = fmaf(xb.y, wv, a5);
        a6 = fmaf(xb.z, wv, a6); a7 = fmaf(xb.w, wv, a7);
    }
    float* pp = part + (size_t)ns * 8 * 64 * 1024;
    pp[((size_t)0 * 64 + o) * 1024 + kl] = a0;
    pp[((size_t)1 * 64 + o) * 1024 + kl] = a1;
    pp[((size_t)2 * 64 + o) * 1024 + kl] = a2;
    pp[((size_t)3 * 64 + o) * 1024 + kl] = a3;
    pp[((size_t)4 * 64 + o) * 1024 + kl] = a4;
    pp[((size_t)5 * 64 + o) * 1024 + kl] = a5;
    pp[((size_t)6 * 64 + o) * 1024 + kl] = a6;
    pp[((size_t)7 * 64 + o) * 1024 + kl] = a7;
}

// t2[b][k][w][o] = sum_l Dt[w][l] * om[b][o][k*32+l]; om = sum of 3 part slices
template<int O>
__global__ void k_inv1(const float* __restrict__ part, float* __restrict__ t2,
                       const float* __restrict__ dt){
    __shared__ float oms[32 * 65];
    const int N = 8 * 64 * 1024;
    int wc = blockIdx.x, k = blockIdx.y, b = blockIdx.z;
    int t = threadIdx.x;
    for (int e = t; e < 2048; e += 256){
        int o_ = e >> 5, l = e & 31;
        int idx = ((b * 64 + o_) << 10) + k * 32 + l;
        oms[l * 65 + o_] = part[idx] + part[N + idx] + part[2 * N + idx];
    }
    __syncthreads();
    int o  = t & 63;
    int wg = __builtin_amdgcn_readfirstlane(t >> 6);
    int wbase = wc * 32 + wg * 8;
    float acc[8];
    #pragma unroll
    for (int wj = 0; wj < 8; wj++) acc[wj] = 0.f;
    for (int l = 0; l < 32; l++){
        float ov = oms[l * 65 + o];
        #pragma unroll
        for (int wj = 0; wj < 8; wj++)
            acc[wj] = fmaf(dt[(wbase + wj) * KPAD + l], ov, acc[wj]);
    }
    if (o < O){
        #pragma unroll
        for (int wj = 0; wj < 8; wj++)
            t2[(((size_t)b * 32 + k) * S + wbase + wj) * 64 + o] = acc[wj];
    }
}

// MFMA k_fused. Block = 32 hh x 2 w x 64 o, 4 waves; wave n: w = n>>1, o-half = n&1.
// acc[32 hh][32 o] = DT[32 hh][32 k] @ t2[k][(w,o)]  (2 K-steps)
//                  + X_w[32 hh][64 i] @ pw^T[i][o]   (4 K-steps, CONV only)
// split-bf16 (hi+lo, 3 MFMAs per step) keeps fp32-level accuracy.
// Fragment maps (guide §3): A/B lane l -> row/col l&31, k (l>>5)*8+j;
// C/D reg r -> row (r&3)+8(r>>2)+4(l>>5), col l&31.
template<bool CONV>
__global__ __launch_bounds__(256, 3) void k_fused(
        const float* __restrict__ t2, float* __restrict__ h,
        const short* __restrict__ pwh, const short* __restrict__ pwl,
        const float* __restrict__ pb,
        const short* __restrict__ dth, const short* __restrict__ dtl){
    __shared__ short t2fh[4 * 2 * 64 * 8];                 // [n][ks][l][j] 8 KB
    __shared__ short t2fl[4 * 2 * 64 * 8];
    __shared__ short hsfh[CONV ? 2 * 4 * 64 * 8 : 1];      // [w][ks][l][j] 8 KB
    __shared__ short hsfl[CONV ? 2 * 4 * 64 * 8 : 1];
    __shared__ float hres[CONV ? 64 * 64 : 1];             // [px][i] f32 16 KB
    int ht = blockIdx.x, wt = blockIdx.y, b = blockIdx.z;
    int t = threadIdx.x;

    // stage t2 tile as B-fragments (element (k,w,o) -> n=(w<<1)|(o>>5),
    // l=(o&31)+32*((k&15)>=8), ks=k>>4, j=k&7)
    for (int e = t; e < 1024; e += 256){
        int k = e >> 5, r = e & 31;
        float4 v = *(const float4*)(t2 +
            ((size_t)(b * 32 + k) * S + wt * 2 + (r >> 4)) * 64 + (r & 15) * 4);
        int ks = k >> 4, j = k & 7;
        int lh = ((k & 15) >= 8) ? 32 : 0;
        int wl = r >> 4;
        float xs[4] = {v.x, v.y, v.z, v.w};
        #pragma unroll
        for (int q = 0; q < 4; q++){
            int o = (r & 15) * 4 + q;
            int n = (wl << 1) | (o >> 5);
            int idx = ((n * 2 + ks) * 64 + (o & 31) + lh) * 8 + j;
            short hi, lo; split_bf(xs[q], hi, lo);
            t2fh[idx] = hi; t2fl[idx] = lo;
        }
    }
    if (CONV){
        // stage h tile: f32 residual + A-fragments (element (hh,w,i) ->
        // ks=i>>4, l=hh+32*((i&15)>=8), j=i&7).  64 px x 16 float4 = 1024 iters.
        const float* hbase = h + (((size_t)b * S + ht * 32) * S + wt * 2) * 64;
        for (int e = t; e < 1024; e += 256){
            int px = e >> 4, i4 = e & 15;
            int hh = px >> 1, wl = px & 1;
            float4 v = *(const float4*)(hbase + ((size_t)hh * S + wl) * 64 + i4 * 4);
            *(float4*)(hres + px * 64 + i4 * 4) = v;
            int ks = i4 >> 2;
            int lh = ((i4 & 3) >= 2) ? 32 : 0;
            int jb = (i4 & 1) * 4;
            int base = ((wl * 4 + ks) * 64 + hh + lh) * 8 + jb;
            short h0,l0,h1,l1,h2,l2,h3,l3;
            split_bf(v.x, h0, l0); split_bf(v.y, h1, l1);
            split_bf(v.z, h2, l2); split_bf(v.w, h3, l3);
            hsfh[base+0]=h0; hsfh[base+1]=h1; hsfh[base+2]=h2; hsfh[base+3]=h3;
            hsfl[base+0]=l0; hsfl[base+1]=l1; hsfl[base+2]=l2; hsfl[base+3]=l3;
        }
    }
    __syncthreads();

    int l = t & 63;
    int n = t >> 6;
    int oh = n & 1, wl = n >> 1;
    f32x16 acc = {0,0,0,0,0,0,0,0,0,0,0,0,0,0,0,0};

    // DCT matmul: A = DT rows hh0.., B = staged t2 fragments
    int hh0 = ht * 32;
    #pragma unroll
    for (int ks = 0; ks < 2; ks++){
        int aoff = (hh0 + (l & 31)) * KPB + ks * 16 + (l >> 5) * 8;
        bfrag ah = *(const bfrag*)(dth + aoff);
        bfrag al = *(const bfrag*)(dtl + aoff);
        int boff = ((n * 2 + ks) * 64 + l) * 8;
        bfrag bh = *(const bfrag*)(t2fh + boff);
        bfrag bl = *(const bfrag*)(t2fl + boff);
        acc = __builtin_amdgcn_mfma_f32_32x32x16_bf16(ah, bh, acc, 0, 0, 0);
        acc = __builtin_amdgcn_mfma_f32_32x32x16_bf16(ah, bl, acc, 0, 0, 0);
        acc = __builtin_amdgcn_mfma_f32_32x32x16_bf16(al, bh, acc, 0, 0, 0);
    }

    if (CONV){
        // conv matmul: A = staged X_w fragments, B = pre-split pw[o][i]
        #pragma unroll
        for (int ks = 0; ks < 4; ks++){
            int aoff = ((wl * 4 + ks) * 64 + l) * 8;
            bfrag ah = *(const bfrag*)(hsfh + aoff);
            bfrag al = *(const bfrag*)(hsfl + aoff);
            int boff = (oh * 32 + (l & 31)) * 64 + ks * 16 + (l >> 5) * 8;
            bfrag bh = *(const bfrag*)(pwh + boff);
            bfrag bl = *(const bfrag*)(pwl + boff);
            acc = __builtin_amdgcn_mfma_f32_32x32x16_bf16(ah, bh, acc, 0, 0, 0);
            acc = __builtin_amdgcn_mfma_f32_32x32x16_bf16(ah, bl, acc, 0, 0, 0);
            acc = __builtin_amdgcn_mfma_f32_32x32x16_bf16(al, bh, acc, 0, 0, 0);
        }
        int o = oh * 32 + (l & 31);
        float pbv = pb[o];
        #pragma unroll
        for (int r = 0; r < 16; r++){
            int row = (r & 3) + 8 * (r >> 2) + 4 * (l >> 5);
            float res = hres[(row * 2 + wl) * 64 + o];
            size_t pix = ((size_t)b * S + ht * 32 + row) * S + wt * 2 + wl;
            h[pix * 64 + o] = res + gelu_f(acc[r] + pbv);
        }
    } else {
        int o = oh * 32 + (l & 31);
        if (o < 61){
            #pragma unroll
            for (int r = 0; r < 16; r++){
                int row = (r & 3) + 8 * (r >> 2) + 4 * (l >> 5);
                size_t pix = ((size_t)b * S + ht * 32 + row) * S + wt * 2 + wl;
                h[pix * 64 + 3 + o] = gelu_f(acc[r]);
            }
        }
    }
}

// out[px] = gelu(h_px @ fc1 + b1) @ fc2 + b2
__global__ void k_mlp(const float* __restrict__ h, const float* __restrict__ fc1w,
                      const float* __restrict__ fc1b, const float* __restrict__ fc2w,
                      const float* __restrict__ fc2b, float* __restrict__ out){
    __shared__ float hs[64 * 65];
    __shared__ float red[256];
    size_t base = (size_t)blockIdx.x * 64;   // first pixel of this block
    int t = threadIdx.x;
    const float* hrow = h + base * 64;
    for (int e = t; e < 4096; e += 256){
        int p = e >> 6, i = e & 63;
        hs[p * 65 + i] = hrow[e];
    }
    __syncthreads();
    int p = t & 63;
    int q = __builtin_amdgcn_readfirstlane(t >> 6);   // wave-uniform j-chunk
    float acc[32];
    const float* b1 = fc1b + q * 32;
    #pragma unroll
    for (int j = 0; j < 32; j++) acc[j] = b1[j];
    for (int i = 0; i < 64; i++){
        float hv = hs[p * 65 + i];
        const float* f1 = fc1w + i * 128 + q * 32;    // wave-uniform -> s_load
        #pragma unroll
        for (int j = 0; j < 32; j++) acc[j] = fmaf(hv, f1[j], acc[j]);
    }
    const float* f2 = fc2w + q * 32;
    float y = 0.f;
    #pragma unroll
    for (int j = 0; j < 32; j++) y = fmaf(gelu_f(acc[j]), f2[j], y);
    red[t] = y;
    __syncthreads();
    if (t < 64){
        out[base + t] = red[t] + red[64 + t] + red[128 + t] + red[192 + t] + fc2b[0];
    }
}

extern "C" void kernel_launch(void* const* d_in, const int* in_sizes, int n_in,
                              void* d_out, int out_size, void* d_ws, size_t ws_size,
                              hipStream_t stream) {
    const float* x    = (const float*)d_in[0];
    const float* wl   = (const float*)d_in[1];
    const float* wc[4] = {(const float*)d_in[2], (const float*)d_in[3],
                          (const float*)d_in[4], (const float*)d_in[5]};
    const float* pw[4] = {(const float*)d_in[6], (const float*)d_in[8],
                          (const float*)d_in[10], (const float*)d_in[12]};
    const float* pb[4] = {(const float*)d_in[7], (const float*)d_in[9],
                          (const float*)d_in[11], (const float*)d_in[13]};
    const float* fc1w = (const float*)d_in[14];
    const float* fc1b = (const float*)d_in[15];
    const float* fc2w = (const float*)d_in[16];
    const float* fc2b = (const float*)d_in[17];
    float* out = (float*)d_out;

    char* ws = (char*)d_ws;
    size_t off = 0;
    float* dt   = (float*)(ws + off); off += (size_t)S * KPAD * 4;              // 36,864
    short* dth  = (short*)(ws + off); off += (size_t)S * KPB * 2;               // 20,480
    short* dtl  = (short*)(ws + off); off += (size_t)S * KPB * 2;               // 20,480
    short* pwh  = (short*)(ws + off); off += (size_t)4 * 4096 * 2;              // 32,768
    short* pwl  = (short*)(ws + off); off += (size_t)4 * 4096 * 2;              // 32,768
    float* h    = (float*)(ws + off); off += (size_t)BB * S * S * W64 * 4;      // 134,217,728
    float* tmp1 = (float*)(ws + off); off += (size_t)BB * PP * S * W64 * 4;     // 17,825,792
    float* bp   = (float*)(ws + off); off += (size_t)BB * PP * PP * W64 * 4;    // 2,367,488
    float* xp   = (float*)(ws + off); off += (size_t)576 * 1024 * 8 * 4;        // 18,874,368
    float* part = (float*)(ws + off); off += (size_t)3 * 8 * 64 * 1024 * 4;     // 6,291,456
    float* t2   = (float*)(ws + off); off += (size_t)BB * 32 * S * W64 * 4;     // 16,777,216

    k_init_dt<<<(S * KPB + 255) / 256, 256, 0, stream>>>(dt, dth, dtl);
    for (int i = 0; i < 4; i++)
        k_prep_pw<<<16, 256, 0, stream>>>(pw[i], pwh + i * 4096, pwl + i * 4096);
    k_copy_x<<<(BB * S * S * CIN + 255) / 256, 256, 0, stream>>>(x, h);

    // ---- block 0: h[:, :, :, 3:] = gelu(pseudo_spectra(x, wl, 61)) ----
    k_fwd1<3><<<dim3(3, BB), 256, 0, stream>>>(x, tmp1, dt);
    k_fwd2_3<<<dim3(1, BB), 256, 0, stream>>>(tmp1, bp, dt);
    k_xp_gather<3, 3><<<dim3(32, 1), 256, 0, stream>>>(bp, xp);
    k_om<27, 61><<<768, 256, 0, stream>>>(xp, wl, part);
    k_inv1<61><<<dim3(8, 32, BB), 256, 0, stream>>>(part, t2, dt);
    k_fused<false><<<dim3(8, 128, BB), 256, 0, stream>>>(
        t2, h, nullptr, nullptr, nullptr, dth, dtl);

    // ---- blocks 1..4 ----
    for (int blk = 0; blk < 4; blk++){
        k_fwd1<64><<<dim3(64, BB), 256, 0, stream>>>(h, tmp1, dt);
        k_fwd2_64<<<dim3(PP, BB), 256, 0, stream>>>(tmp1, bp, dt);
        k_xp_gather<64, 16><<<dim3(32, 4), 256, 0, stream>>>(bp, xp);
        k_om<576, 64><<<768, 256, 0, stream>>>(xp, wc[blk], part);
        k_inv1<64><<<dim3(8, 32, BB), 256, 0, stream>>>(part, t2, dt);
        k_fused<true><<<dim3(8, 128, BB), 256, 0, stream>>>(
            t2, h, pwh + blk * 4096, pwl + blk * 4096, pb[blk], dth, dtl);
    }

    // ---- final MLP (T_fwd(T_inv2(.)) is identity for the orthonormal DCT) ----
    k_mlp<<<dim3(BB * S * S / 64), 256, 0, stream>>>(h, fc1w, fc1b, fc2w, fc2b, out);
}

// Round 9
// 1326.675 us; speedup vs baseline: 1.6891x; 1.1214x over previous
//
#include <hip/hip_runtime.h>
#include <math.h>

#define BB 8
#define S 256
#define CIN 3
#define W64 64
#define MODES 32
#define PP 34     // MODES + BW - 1
#define KPAD 36   // padded leading dim for f32 Dt
#define KPB 40    // padded leading dim for bf16 Dt tables (16B-aligned frag loads)

typedef __attribute__((ext_vector_type(8))) short bfrag;    // 8 bf16 raw bits
typedef __attribute__((ext_vector_type(16))) float f32x16;

// fast erf-based gelu: A&S 7.1.26, |erf err| <= 1.5e-7 (libm erff is ~40 insts)
__device__ __forceinline__ float gelu_f(float x){
    float z = fabsf(x) * 0.70710678118654752f;
    float t = 1.0f / (1.0f + 0.3275911f * z);
    float p = ((((1.061405429f * t - 1.453152027f) * t) + 1.421413741f) * t
               - 0.284496736f) * t + 0.254829592f;
    float e = __expf(-z * z);
    float erf = 1.0f - p * t * e;
    erf = copysignf(erf, x);
    return 0.5f * x * (1.0f + erf);
}

// split x into bf16 hi + bf16 lo (round-to-nearest-even), x ~= hi + lo
__device__ __forceinline__ void split_bf(float x, short &hi, short &lo){
    unsigned u = __float_as_uint(x);
    unsigned r = u + 0x7FFFu + ((u >> 16) & 1u);
    hi = (short)(r >> 16);
    float hf = __uint_as_float(r & 0xFFFF0000u);
    float l = x - hf;
    unsigned v = __float_as_uint(l);
    unsigned s2 = v + 0x7FFFu + ((v >> 16) & 1u);
    lo = (short)(s2 >> 16);
}

// dt[h*36+k] = DCT[k,h] f32; dth/dtl[h*40+k] = bf16 hi/lo split
__global__ void k_init_dt(float* __restrict__ dt, short* __restrict__ dth,
                          short* __restrict__ dtl){
    int tid = blockIdx.x * 256 + threadIdx.x;
    if (tid >= S * KPB) return;
    int h = tid / KPB, k = tid % KPB;
    double v = 0.0;
    if (k < PP) {
        v = sqrt(2.0 / (double)S) * cos(3.14159265358979323846 * (h + 0.5) * k / (double)S);
        if (k == 0) v *= 0.70710678118654752440;
    }
    float f = (float)v;
    if (k < KPAD) dt[h * KPAD + k] = f;
    short hi, lo; split_bf(f, hi, lo);
    dth[tid] = hi; dtl[tid] = lo;
}

// split a 64x64 conv weight into bf16 hi/lo (layout preserved: pw[o][i])
__global__ void k_prep_pw(const float* __restrict__ pw, short* __restrict__ pwh,
                          short* __restrict__ pwl){
    int e = blockIdx.x * 256 + threadIdx.x;
    if (e >= 4096) return;
    short hi, lo; split_bf(pw[e], hi, lo);
    pwh[e] = hi; pwl[e] = lo;
}

// split fc1 (64 i x 128 j) into B-fragment-ordered hi/lo:
// idx = ((n*4+ks)*64 + l)*8 + jr ; n=j>>5, ks=i>>4, l=(j&31)+32*((i&15)>=8), jr=i&7
__global__ void k_prep_fc1(const float* __restrict__ fc1w, short* __restrict__ f1h,
                           short* __restrict__ f1l){
    int e = blockIdx.x * 256 + threadIdx.x;
    if (e >= 8192) return;
    int i = e >> 7, j = e & 127;
    int n = j >> 5, ks = i >> 4;
    int l = (j & 31) + (((i & 15) >= 8) ? 32 : 0);
    int jr = i & 7;
    int idx = ((n * 4 + ks) * 64 + l) * 8 + jr;
    short hi, lo; split_bf(fc1w[e], hi, lo);
    f1h[idx] = hi; f1l[idx] = lo;
}

// x (B,S,S,3) -> h channels 0..2 (channels-last h: (B,S,S,64))
__global__ void k_copy_x(const float* __restrict__ x, float* __restrict__ h){
    int e = blockIdx.x * 256 + threadIdx.x;
    if (e >= BB * S * S * CIN) return;
    int px = e / CIN, c = e % CIN;
    h[(size_t)px * W64 + c] = x[e];
}

// tmp1[b][k][w][c] = sum_h Dt[h][k] * src[b][h][w][c]   (k < 34)
template<int C>
__global__ void k_fwd1(const float* __restrict__ src, float* __restrict__ tmp1,
                       const float* __restrict__ dt){
    int b = blockIdx.y;
    int idx = blockIdx.x * 256 + threadIdx.x;   // flat (w, c)
    if (idx >= S * C) return;
    float acc[PP];
    #pragma unroll
    for (int k = 0; k < PP; k++) acc[k] = 0.f;
    const float* sp = src + (size_t)b * S * S * C + idx;
    for (int hh = 0; hh < S; hh++){
        float v = sp[(size_t)hh * S * C];
        const float* dr = dt + hh * KPAD;
        #pragma unroll
        for (int k = 0; k < PP; k++) acc[k] = fmaf(dr[k], v, acc[k]);
    }
    float* op = tmp1 + (size_t)b * PP * S * C + idx;
    #pragma unroll
    for (int k = 0; k < PP; k++) op[(size_t)k * S * C] = acc[k];
}

// bp[b][k][l][c] = sum_w Dt[w][l] * tmp1[b][k][w][c]   (C=3 path, tiny)
__global__ void k_fwd2_3(const float* __restrict__ tmp1, float* __restrict__ bp,
                         const float* __restrict__ dt){
    const int C = 3;
    int b = blockIdx.y;
    int idx = blockIdx.x * 256 + threadIdx.x;   // flat (k, c)
    if (idx >= PP * C) return;
    int k = idx / C, c = idx % C;
    float acc[PP];
    #pragma unroll
    for (int l = 0; l < PP; l++) acc[l] = 0.f;
    const float* sp = tmp1 + ((size_t)b * PP + k) * S * C + c;
    for (int w = 0; w < S; w++){
        float v = sp[(size_t)w * C];
        const float* dr = dt + w * KPAD;
        #pragma unroll
        for (int l = 0; l < PP; l++) acc[l] = fmaf(dr[l], v, acc[l]);
    }
    float* op = bp + ((size_t)b * PP + k) * PP * C + c;
    #pragma unroll
    for (int l = 0; l < PP; l++) op[(size_t)l * C] = acc[l];
}

// C=64: block = (k, b), 4 waves each own a 64-wide w-segment, LDS reduce.
__global__ __launch_bounds__(256, 4) void k_fwd2_64(
        const float* __restrict__ tmp1, float* __restrict__ bp,
        const float* __restrict__ dt){
    const int C = 64;
    __shared__ float red[4 * PP * 66];   // 35.9 KB
    int k = blockIdx.x, b = blockIdx.y;
    int t = threadIdx.x;
    int c = t & 63;
    int ws = __builtin_amdgcn_readfirstlane(t >> 6);
    float acc[PP];
    #pragma unroll
    for (int l = 0; l < PP; l++) acc[l] = 0.f;
    const float* sp = tmp1 + ((size_t)b * PP + k) * S * C + c;
    for (int w = ws * 64; w < ws * 64 + 64; w++){
        float v = sp[(size_t)w * C];
        const float* dr = dt + w * KPAD;
        #pragma unroll
        for (int l = 0; l < PP; l++) acc[l] = fmaf(dr[l], v, acc[l]);
    }
    #pragma unroll
    for (int l = 0; l < PP; l++) red[(ws * PP + l) * 66 + c] = acc[l];
    __syncthreads();
    float* op = bp + ((size_t)b * PP + k) * PP * C;
    for (int e = t; e < PP * C; e += 256){
        int l = e >> 6, cc = e & 63;
        op[e] = red[(0 * PP + l) * 66 + cc] + red[(1 * PP + l) * 66 + cc]
              + red[(2 * PP + l) * 66 + cc] + red[(3 * PP + l) * 66 + cc];
    }
}

// xp[i][kl][b] = bp[b][k+i_][l+j_][c],  i = c*9 + i_*3 + j_, kl = k*32 + l
template<int C, int CC>
__global__ void k_xp_gather(const float* __restrict__ bp, float* __restrict__ xp){
    __shared__ float lds[8 * 3 * PP * (CC + 1)];
    int k  = blockIdx.x;           // 0..31
    int c0 = blockIdx.y * CC;
    int t  = threadIdx.x;
    const int TOT = 8 * 3 * PP * CC;
    for (int e = t; e < TOT; e += 256){
        int b   = e / (3 * PP * CC);
        int r   = e % (3 * PP * CC);
        int row = r / (PP * CC);
        int r2  = r % (PP * CC);
        int l   = r2 / CC;
        int c   = r2 % CC;
        lds[((b * 3 + row) * PP + l) * (CC + 1) + c] =
            bp[(((size_t)b * PP + (k + row)) * PP + l) * C + c0 + c];
    }
    __syncthreads();
    int l = t >> 3;   // 0..31
    int b = t & 7;
    for (int c = 0; c < CC; c++){
        #pragma unroll
        for (int ij = 0; ij < 9; ij++){
            int i_ = ij / 3, j_ = ij % 3;
            int i  = (c0 + c) * 9 + ij;
            float v = lds[((b * 3 + i_) * PP + (l + j_)) * (CC + 1) + c];
            xp[((size_t)i * 1024 + k * 32 + l) * 8 + b] = v;
        }
    }
}

// part[ns][b][o][kl] = sum_{i in slice ns} xp[i][kl][b] * w[i][o][kl]
template<int ITOT, int O>
__global__ void k_om(const float* __restrict__ xp, const float* __restrict__ w,
                     float* __restrict__ part){
    int bx  = blockIdx.x;
    int klt = bx & 31;
    int ot  = (bx >> 5) & 7;
    int ns  = bx >> 8;              // 0..2
    const int ILEN = ITOT / 3;
    int t  = threadIdx.x;
    int kl = klt * 32 + (t & 31);
    int o  = ot * 8 + (t >> 5);
    if (o >= O) return;
    float a0=0,a1=0,a2=0,a3=0,a4=0,a5=0,a6=0,a7=0;
    const float* xpp = xp + ((size_t)(ns * ILEN) * 1024 + kl) * 8;
    const float* wp  = w + ((size_t)(ns * ILEN) * O + o) * 1024 + kl;
    #pragma unroll 4
    for (int i = 0; i < ILEN; i++){
        float4 xa = *(const float4*)(xpp + (size_t)i * 8192);
        float4 xb = *(const float4*)(xpp + (size_t)i * 8192 + 4);
        float wv  = wp[(size_t)i * O * 1024];
        a0 = fmaf(xa.x, wv, a0); a1 = fmaf(xa.y, wv, a1);
        a2 = fmaf(xa.z, wv, a2); a3 = fmaf(xa.w, wv, a3);
        a4 = fmaf(xb.x, wv, a4); a5 = fmaf(xb.y, wv, a5);
        a6 = fmaf(xb.z, wv, a6); a7 = fmaf(xb.w, wv, a7);
    }
    float* pp = part + (size_t)ns * 8 * 64 * 1024;
    pp[((size_t)0 * 64 + o) * 1024 + kl] = a0;
    pp[((size_t)1 * 64 + o) * 1024 + kl] = a1;
    pp[((size_t)2 * 64 + o) * 1024 + kl] = a2;
    pp[((size_t)3 * 64 + o) * 1024 + kl] = a3;
    pp[((size_t)4 * 64 + o) * 1024 + kl] = a4;
    pp[((size_t)5 * 64 + o) * 1024 + kl] = a5;
    pp[((size_t)6 * 64 + o) * 1024 + kl] = a6;
    pp[((size_t)7 * 64 + o) * 1024 + kl] = a7;
}

// t2[b][k][w][o] = sum_l Dt[w][l] * om[b][o][k*32+l]; om = sum of 3 part slices
template<int O>
__global__ void k_inv1(const float* __restrict__ part, float* __restrict__ t2,
                       const float* __restrict__ dt){
    __shared__ float oms[32 * 65];
    const int N = 8 * 64 * 1024;
    int wc = blockIdx.x, k = blockIdx.y, b = blockIdx.z;
    int t = threadIdx.x;
    for (int e = t; e < 2048; e += 256){
        int o_ = e >> 5, l = e & 31;
        int idx = ((b * 64 + o_) << 10) + k * 32 + l;
        oms[l * 65 + o_] = part[idx] + part[N + idx] + part[2 * N + idx];
    }
    __syncthreads();
    int o  = t & 63;
    int wg = __builtin_amdgcn_readfirstlane(t >> 6);
    int wbase = wc * 32 + wg * 8;
    float acc[8];
    #pragma unroll
    for (int wj = 0; wj < 8; wj++) acc[wj] = 0.f;
    for (int l = 0; l < 32; l++){
        float ov = oms[l * 65 + o];
        #pragma unroll
        for (int wj = 0; wj < 8; wj++)
            acc[wj] = fmaf(dt[(wbase + wj) * KPAD + l], ov, acc[wj]);
    }
    if (o < O){
        #pragma unroll
        for (int wj = 0; wj < 8; wj++)
            t2[(((size_t)b * 32 + k) * S + wbase + wj) * 64 + o] = acc[wj];
    }
}

// MFMA k_fused, ht-loop version. Block = (wt, b); loops ht=0..7.
// t2 fragments (hh-independent) are split ONCE per block (R8 split them 8x).
// Per ht: stage h tile as A-frags + f32 residual, DCT mfma (2 ks) + conv mfma
// (4 ks), epilogue. split-bf16 (hi+lo, 3 MFMAs/step) keeps fp32-level accuracy.
template<bool CONV>
__global__ __launch_bounds__(256, 3) void k_fused(
        const float* __restrict__ t2, float* __restrict__ h,
        const short* __restrict__ pwh, const short* __restrict__ pwl,
        const float* __restrict__ pb,
        const short* __restrict__ dth, const short* __restrict__ dtl){
    __shared__ short t2fh[4 * 2 * 64 * 8];                 // [n][ks][l][j] 8 KB
    __shared__ short t2fl[4 * 2 * 64 * 8];
    __shared__ short hsfh[CONV ? 2 * 4 * 64 * 8 : 1];      // [w][ks][l][j] 8 KB
    __shared__ short hsfl[CONV ? 2 * 4 * 64 * 8 : 1];
    __shared__ float hres[CONV ? 64 * 64 : 1];             // [px][i] f32 16 KB
    int wt = blockIdx.x, b = blockIdx.y;
    int t = threadIdx.x;

    // stage t2 tile as B-fragments (element (k,w,o) -> n=(w<<1)|(o>>5),
    // l=(o&31)+32*((k&15)>=8), ks=k>>4, j=k&7)
    for (int e = t; e < 1024; e += 256){
        int k = e >> 5, r = e & 31;
        float4 v = *(const float4*)(t2 +
            ((size_t)(b * 32 + k) * S + wt * 2 + (r >> 4)) * 64 + (r & 15) * 4);
        int ks = k >> 4, j = k & 7;
        int lh = ((k & 15) >= 8) ? 32 : 0;
        int wl_ = r >> 4;
        float xs[4] = {v.x, v.y, v.z, v.w};
        #pragma unroll
        for (int q = 0; q < 4; q++){
            int o = (r & 15) * 4 + q;
            int n = (wl_ << 1) | (o >> 5);
            int idx = ((n * 2 + ks) * 64 + (o & 31) + lh) * 8 + j;
            short hi, lo; split_bf(xs[q], hi, lo);
            t2fh[idx] = hi; t2fl[idx] = lo;
        }
    }

    int l = t & 63;
    int n = t >> 6;
    int oh = n & 1, wl = n >> 1;
    int o = oh * 32 + (l & 31);

    for (int ht = 0; ht < 8; ht++){
        if (CONV){
            __syncthreads();   // prev-iter epilogue done with hres/hsf
            const float* hbase = h + (((size_t)b * S + ht * 32) * S + wt * 2) * 64;
            for (int e = t; e < 1024; e += 256){
                int px = e >> 4, i4 = e & 15;
                int hh = px >> 1, wl_ = px & 1;
                float4 v = *(const float4*)(hbase + ((size_t)hh * S + wl_) * 64 + i4 * 4);
                *(float4*)(hres + px * 64 + i4 * 4) = v;
                int ks = i4 >> 2;
                int lh = ((i4 & 3) >= 2) ? 32 : 0;
                int jb = (i4 & 1) * 4;
                int base2 = ((wl_ * 4 + ks) * 64 + hh + lh) * 8 + jb;
                short h0,l0,h1,l1,h2,l2,h3,l3;
                split_bf(v.x, h0, l0); split_bf(v.y, h1, l1);
                split_bf(v.z, h2, l2); split_bf(v.w, h3, l3);
                hsfh[base2+0]=h0; hsfh[base2+1]=h1; hsfh[base2+2]=h2; hsfh[base2+3]=h3;
                hsfl[base2+0]=l0; hsfl[base2+1]=l1; hsfl[base2+2]=l2; hsfl[base2+3]=l3;
            }
        }
        __syncthreads();

        f32x16 acc = {0,0,0,0,0,0,0,0,0,0,0,0,0,0,0,0};

        // DCT matmul: A = DT rows ht*32.., B = staged t2 fragments
        int hh0 = ht * 32;
        #pragma unroll
        for (int ks = 0; ks < 2; ks++){
            int aoff = (hh0 + (l & 31)) * KPB + ks * 16 + (l >> 5) * 8;
            bfrag ah = *(const bfrag*)(dth + aoff);
            bfrag al = *(const bfrag*)(dtl + aoff);
            int boff = ((n * 2 + ks) * 64 + l) * 8;
            bfrag bh = *(const bfrag*)(t2fh + boff);
            bfrag bl = *(const bfrag*)(t2fl + boff);
            acc = __builtin_amdgcn_mfma_f32_32x32x16_bf16(ah, bh, acc, 0, 0, 0);
            acc = __builtin_amdgcn_mfma_f32_32x32x16_bf16(ah, bl, acc, 0, 0, 0);
            acc = __builtin_amdgcn_mfma_f32_32x32x16_bf16(al, bh, acc, 0, 0, 0);
        }

        if (CONV){
            #pragma unroll
            for (int ks = 0; ks < 4; ks++){
                int aoff = ((wl * 4 + ks) * 64 + l) * 8;
                bfrag ah = *(const bfrag*)(hsfh + aoff);
                bfrag al = *(const bfrag*)(hsfl + aoff);
                int boff = (o) * 64 + ks * 16 + (l >> 5) * 8;
                bfrag bh = *(const bfrag*)(pwh + boff);
                bfrag bl = *(const bfrag*)(pwl + boff);
                acc = __builtin_amdgcn_mfma_f32_32x32x16_bf16(ah, bh, acc, 0, 0, 0);
                acc = __builtin_amdgcn_mfma_f32_32x32x16_bf16(ah, bl, acc, 0, 0, 0);
                acc = __builtin_amdgcn_mfma_f32_32x32x16_bf16(al, bh, acc, 0, 0, 0);
            }
            float pbv = pb[o];
            #pragma unroll
            for (int r = 0; r < 16; r++){
                int row = (r & 3) + 8 * (r >> 2) + 4 * (l >> 5);
                float res = hres[(row * 2 + wl) * 64 + o];
                size_t pix = ((size_t)b * S + ht * 32 + row) * S + wt * 2 + wl;
                h[pix * 64 + o] = res + gelu_f(acc[r] + pbv);
            }
        } else {
            if (o < 61){
                #pragma unroll
                for (int r = 0; r < 16; r++){
                    int row = (r & 3) + 8 * (r >> 2) + 4 * (l >> 5);
                    size_t pix = ((size_t)b * S + ht * 32 + row) * S + wt * 2 + wl;
                    h[pix * 64 + 3 + o] = gelu_f(acc[r]);
                }
            }
        }
    }
}

// MFMA k_mlp: P[64px][128j] = h[64px][64i] @ fc1[64i][128j]; out = gelu(P+b1)@fc2+b2.
// 4 waves: wave w -> row-tile m=w>>1, col-tiles n0=(w&1)*2, n0+1 (24 MFMAs/wave
// replaces 2048 VALU FMAs/thread). Row-sum via padded LDS.
__global__ __launch_bounds__(256, 4) void k_mlp(
        const float* __restrict__ h, const short* __restrict__ f1h,
        const short* __restrict__ f1l, const float* __restrict__ fc1b,
        const float* __restrict__ fc2w, const float* __restrict__ fc2b,
        float* __restrict__ out){
    __shared__ short ah_[2 * 4 * 64 * 8];   // [m][ks][l][j] hi, 8 KB
    __shared__ short al_[2 * 4 * 64 * 8];
    __shared__ float red[2 * 64 * 33];      // [pair][row][col], 16.9 KB
    size_t base = (size_t)blockIdx.x * 64;
    int t = threadIdx.x;
    const float* hrow = h + base * 64;
    // stage h (64px x 64i) as split-bf16 A-fragments
    for (int e = t; e < 1024; e += 256){
        int px = e >> 4, i4 = e & 15;
        float4 v = *(const float4*)(hrow + px * 64 + i4 * 4);
        int ks = i4 >> 2;
        int lh = ((i4 & 3) >= 2) ? 32 : 0;
        int jb = (i4 & 1) * 4;
        int m = px >> 5;
        int idx = ((m * 4 + ks) * 64 + (px & 31) + lh) * 8 + jb;
        short h0,l0,h1,l1,h2,l2,h3,l3;
        split_bf(v.x, h0, l0); split_bf(v.y, h1, l1);
        split_bf(v.z, h2, l2); split_bf(v.w, h3, l3);
        ah_[idx+0]=h0; ah_[idx+1]=h1; ah_[idx+2]=h2; ah_[idx+3]=h3;
        al_[idx+0]=l0; al_[idx+1]=l1; al_[idx+2]=l2; al_[idx+3]=l3;
    }
    __syncthreads();
    int l = t & 63;
    int w = t >> 6;
    int m = w >> 1;
    int n0 = (w & 1) * 2;
    f32x16 acc0 = {0,0,0,0,0,0,0,0,0,0,0,0,0,0,0,0};
    f32x16 acc1 = {0,0,0,0,0,0,0,0,0,0,0,0,0,0,0,0};
    #pragma unroll
    for (int ks = 0; ks < 4; ks++){
        int aoff = ((m * 4 + ks) * 64 + l) * 8;
        bfrag ah = *(const bfrag*)(ah_ + aoff);
        bfrag al = *(const bfrag*)(al_ + aoff);
        int b0off = ((n0 * 4 + ks) * 64 + l) * 8;
        int b1off = (((n0 + 1) * 4 + ks) * 64 + l) * 8;
        bfrag b0h = *(const bfrag*)(f1h + b0off);
        bfrag b0l = *(const bfrag*)(f1l + b0off);
        bfrag b1h = *(const bfrag*)(f1h + b1off);
        bfrag b1l = *(const bfrag*)(f1l + b1off);
        acc0 = __builtin_amdgcn_mfma_f32_32x32x16_bf16(ah, b0h, acc0, 0, 0, 0);
        acc0 = __builtin_amdgcn_mfma_f32_32x32x16_bf16(ah, b0l, acc0, 0, 0, 0);
        acc0 = __builtin_amdgcn_mfma_f32_32x32x16_bf16(al, b0h, acc0, 0, 0, 0);
        acc1 = __builtin_amdgcn_mfma_f32_32x32x16_bf16(ah, b1h, acc1, 0, 0, 0);
        acc1 = __builtin_amdgcn_mfma_f32_32x32x16_bf16(ah, b1l, acc1, 0, 0, 0);
        acc1 = __builtin_amdgcn_mfma_f32_32x32x16_bf16(al, b1h, acc1, 0, 0, 0);
    }
    int j0 = n0 * 32 + (l & 31), j1 = j0 + 32;
    float b10 = fc1b[j0], b11 = fc1b[j1];
    float f20 = fc2w[j0], f21 = fc2w[j1];
    float* rb = red + (w & 1) * 64 * 33;
    #pragma unroll
    for (int r = 0; r < 16; r++){
        int row = (r & 3) + 8 * (r >> 2) + 4 * (l >> 5);
        rb[(m * 32 + row) * 33 + (l & 31)] =
            gelu_f(acc0[r] + b10) * f20 + gelu_f(acc1[r] + b11) * f21;
    }
    __syncthreads();
    if (t < 64){
        float s = fc2b[0];
        #pragma unroll
        for (int c = 0; c < 32; c++)
            s += red[t * 33 + c] + red[(64 + t) * 33 + c];
        out[base + t] = s;
    }
}

extern "C" void kernel_launch(void* const* d_in, const int* in_sizes, int n_in,
                              void* d_out, int out_size, void* d_ws, size_t ws_size,
                              hipStream_t stream) {
    const float* x    = (const float*)d_in[0];
    const float* wl   = (const float*)d_in[1];
    const float* wc[4] = {(const float*)d_in[2], (const float*)d_in[3],
                          (const float*)d_in[4], (const float*)d_in[5]};
    const float* pw[4] = {(const float*)d_in[6], (const float*)d_in[8],
                          (const float*)d_in[10], (const float*)d_in[12]};
    const float* pb[4] = {(const float*)d_in[7], (const float*)d_in[9],
                          (const float*)d_in[11], (const float*)d_in[13]};
    const float* fc1w = (const float*)d_in[14];
    const float* fc1b = (const float*)d_in[15];
    const float* fc2w = (const float*)d_in[16];
    const float* fc2b = (const float*)d_in[17];
    float* out = (float*)d_out;

    char* ws = (char*)d_ws;
    size_t off = 0;
    float* dt   = (float*)(ws + off); off += (size_t)S * KPAD * 4;              // 36,864
    short* dth  = (short*)(ws + off); off += (size_t)S * KPB * 2;               // 20,480
    short* dtl  = (short*)(ws + off); off += (size_t)S * KPB * 2;               // 20,480
    short* pwh  = (short*)(ws + off); off += (size_t)4 * 4096 * 2;              // 32,768
    short* pwl  = (short*)(ws + off); off += (size_t)4 * 4096 * 2;              // 32,768
    short* f1h  = (short*)(ws + off); off += (size_t)8192 * 2;                  // 16,384
    short* f1l  = (short*)(ws + off); off += (size_t)8192 * 2;                  // 16,384
    float* h    = (float*)(ws + off); off += (size_t)BB * S * S * W64 * 4;      // 134,217,728
    float* tmp1 = (float*)(ws + off); off += (size_t)BB * PP * S * W64 * 4;     // 17,825,792
    float* bp   = (float*)(ws + off); off += (size_t)BB * PP * PP * W64 * 4;    // 2,367,488
    float* xp   = (float*)(ws + off); off += (size_t)576 * 1024 * 8 * 4;        // 18,874,368
    float* part = (float*)(ws + off); off += (size_t)3 * 8 * 64 * 1024 * 4;     // 6,291,456
    float* t2   = (float*)(ws + off); off += (size_t)BB * 32 * S * W64 * 4;     // 16,777,216

    k_init_dt<<<(S * KPB + 255) / 256, 256, 0, stream>>>(dt, dth, dtl);
    for (int i = 0; i < 4; i++)
        k_prep_pw<<<16, 256, 0, stream>>>(pw[i], pwh + i * 4096, pwl + i * 4096);
    k_prep_fc1<<<32, 256, 0, stream>>>(fc1w, f1h, f1l);
    k_copy_x<<<(BB * S * S * CIN + 255) / 256, 256, 0, stream>>>(x, h);

    // ---- block 0: h[:, :, :, 3:] = gelu(pseudo_spectra(x, wl, 61)) ----
    k_fwd1<3><<<dim3(3, BB), 256, 0, stream>>>(x, tmp1, dt);
    k_fwd2_3<<<dim3(1, BB), 256, 0, stream>>>(tmp1, bp, dt);
    k_xp_gather<3, 3><<<dim3(32, 1), 256, 0, stream>>>(bp, xp);
    k_om<27, 61><<<768, 256, 0, stream>>>(xp, wl, part);
    k_inv1<61><<<dim3(8, 32, BB), 256, 0, stream>>>(part, t2, dt);
    k_fused<false><<<dim3(128, BB), 256, 0, stream>>>(
        t2, h, nullptr, nullptr, nullptr, dth, dtl);

    // ---- blocks 1..4 ----
    for (int blk = 0; blk < 4; blk++){
        k_fwd1<64><<<dim3(64, BB), 256, 0, stream>>>(h, tmp1, dt);
        k_fwd2_64<<<dim3(PP, BB), 256, 0, stream>>>(tmp1, bp, dt);
        k_xp_gather<64, 16><<<dim3(32, 4), 256, 0, stream>>>(bp, xp);
        k_om<576, 64><<<768, 256, 0, stream>>>(xp, wc[blk], part);
        k_inv1<64><<<dim3(8, 32, BB), 256, 0, stream>>>(part, t2, dt);
        k_fused<true><<<dim3(128, BB), 256, 0, stream>>>(
            t2, h, pwh + blk * 4096, pwl + blk * 4096, pb[blk], dth, dtl);
    }

    // ---- final MLP (T_fwd(T_inv2(.)) is identity for the orthonormal DCT) ----
    k_mlp<<<dim3(BB * S * S / 64), 256, 0, stream>>>(h, f1h, f1l, fc1b, fc2w, fc2b, out);
}

// Round 10
// 1267.513 us; speedup vs baseline: 1.7679x; 1.0467x over previous
//
#include <hip/hip_runtime.h>
#include <math.h>

#define BB 8
#define S 256
#define CIN 3
#define W64 64
#define MODES 32
#define PP 34     // MODES + BW - 1
#define KPAD 36   // padded leading dim for f32 Dt
#define KPB 40    // padded leading dim for bf16 Dt tables (16B-aligned frag loads)

typedef __attribute__((ext_vector_type(8))) short bfrag;    // 8 bf16 raw bits
typedef __attribute__((ext_vector_type(16))) float f32x16;

// fast erf-based gelu: A&S 7.1.26, |erf err| <= 1.5e-7 (libm erff is ~40 insts)
__device__ __forceinline__ float gelu_f(float x){
    float z = fabsf(x) * 0.70710678118654752f;
    float t = 1.0f / (1.0f + 0.3275911f * z);
    float p = ((((1.061405429f * t - 1.453152027f) * t) + 1.421413741f) * t
               - 0.284496736f) * t + 0.254829592f;
    float e = __expf(-z * z);
    float erf = 1.0f - p * t * e;
    erf = copysignf(erf, x);
    return 0.5f * x * (1.0f + erf);
}

// split x into bf16 hi + bf16 lo (round-to-nearest-even), x ~= hi + lo
__device__ __forceinline__ void split_bf(float x, short &hi, short &lo){
    unsigned u = __float_as_uint(x);
    unsigned r = u + 0x7FFFu + ((u >> 16) & 1u);
    hi = (short)(r >> 16);
    float hf = __uint_as_float(r & 0xFFFF0000u);
    float l = x - hf;
    unsigned v = __float_as_uint(l);
    unsigned s2 = v + 0x7FFFu + ((v >> 16) & 1u);
    lo = (short)(s2 >> 16);
}

// split 8 floats (two float4) into hi/lo bfrags
__device__ __forceinline__ void split8(float4 a, float4 b, bfrag &hv, bfrag &lv){
    short hi, lo;
    split_bf(a.x, hi, lo); hv[0] = hi; lv[0] = lo;
    split_bf(a.y, hi, lo); hv[1] = hi; lv[1] = lo;
    split_bf(a.z, hi, lo); hv[2] = hi; lv[2] = lo;
    split_bf(a.w, hi, lo); hv[3] = hi; lv[3] = lo;
    split_bf(b.x, hi, lo); hv[4] = hi; lv[4] = lo;
    split_bf(b.y, hi, lo); hv[5] = hi; lv[5] = lo;
    split_bf(b.z, hi, lo); hv[6] = hi; lv[6] = lo;
    split_bf(b.w, hi, lo); hv[7] = hi; lv[7] = lo;
}

// dt[h*36+k] = DCT[k,h] f32; dth/dtl[h*40+k] = bf16 hi/lo split
__global__ void k_init_dt(float* __restrict__ dt, short* __restrict__ dth,
                          short* __restrict__ dtl){
    int tid = blockIdx.x * 256 + threadIdx.x;
    if (tid >= S * KPB) return;
    int h = tid / KPB, k = tid % KPB;
    double v = 0.0;
    if (k < PP) {
        v = sqrt(2.0 / (double)S) * cos(3.14159265358979323846 * (h + 0.5) * k / (double)S);
        if (k == 0) v *= 0.70710678118654752440;
    }
    float f = (float)v;
    if (k < KPAD) dt[h * KPAD + k] = f;
    short hi, lo; split_bf(f, hi, lo);
    dth[tid] = hi; dtl[tid] = lo;
}

// split a 64x64 conv weight into bf16 hi/lo (layout preserved: pw[o][i])
__global__ void k_prep_pw(const float* __restrict__ pw, short* __restrict__ pwh,
                          short* __restrict__ pwl){
    int e = blockIdx.x * 256 + threadIdx.x;
    if (e >= 4096) return;
    short hi, lo; split_bf(pw[e], hi, lo);
    pwh[e] = hi; pwl[e] = lo;
}

// split fc1 (64 i x 128 j) into B-fragment-ordered hi/lo:
// idx = ((n*4+ks)*64 + l)*8 + jr ; n=j>>5, ks=i>>4, l=(j&31)+32*((i&15)>=8), jr=i&7
__global__ void k_prep_fc1(const float* __restrict__ fc1w, short* __restrict__ f1h,
                           short* __restrict__ f1l){
    int e = blockIdx.x * 256 + threadIdx.x;
    if (e >= 8192) return;
    int i = e >> 7, j = e & 127;
    int n = j >> 5, ks = i >> 4;
    int l = (j & 31) + (((i & 15) >= 8) ? 32 : 0);
    int jr = i & 7;
    int idx = ((n * 4 + ks) * 64 + l) * 8 + jr;
    short hi, lo; split_bf(fc1w[e], hi, lo);
    f1h[idx] = hi; f1l[idx] = lo;
}

// x (B,S,S,3) -> h channels 0..2 (channels-last h: (B,S,S,64))
__global__ void k_copy_x(const float* __restrict__ x, float* __restrict__ h){
    int e = blockIdx.x * 256 + threadIdx.x;
    if (e >= BB * S * S * CIN) return;
    int px = e / CIN, c = e % CIN;
    h[(size_t)px * W64 + c] = x[e];
}

// tmp1[b][k][w][c] = sum_h Dt[h][k] * src[b][h][w][c]   (k < 34)
template<int C>
__global__ void k_fwd1(const float* __restrict__ src, float* __restrict__ tmp1,
                       const float* __restrict__ dt){
    int b = blockIdx.y;
    int idx = blockIdx.x * 256 + threadIdx.x;   // flat (w, c)
    if (idx >= S * C) return;
    float acc[PP];
    #pragma unroll
    for (int k = 0; k < PP; k++) acc[k] = 0.f;
    const float* sp = src + (size_t)b * S * S * C + idx;
    for (int hh = 0; hh < S; hh++){
        float v = sp[(size_t)hh * S * C];
        const float* dr = dt + hh * KPAD;
        #pragma unroll
        for (int k = 0; k < PP; k++) acc[k] = fmaf(dr[k], v, acc[k]);
    }
    float* op = tmp1 + (size_t)b * PP * S * C + idx;
    #pragma unroll
    for (int k = 0; k < PP; k++) op[(size_t)k * S * C] = acc[k];
}

// bp[b][k][l][c] = sum_w Dt[w][l] * tmp1[b][k][w][c]   (C=3 path, tiny)
__global__ void k_fwd2_3(const float* __restrict__ tmp1, float* __restrict__ bp,
                         const float* __restrict__ dt){
    const int C = 3;
    int b = blockIdx.y;
    int idx = blockIdx.x * 256 + threadIdx.x;   // flat (k, c)
    if (idx >= PP * C) return;
    int k = idx / C, c = idx % C;
    float acc[PP];
    #pragma unroll
    for (int l = 0; l < PP; l++) acc[l] = 0.f;
    const float* sp = tmp1 + ((size_t)b * PP + k) * S * C + c;
    for (int w = 0; w < S; w++){
        float v = sp[(size_t)w * C];
        const float* dr = dt + w * KPAD;
        #pragma unroll
        for (int l = 0; l < PP; l++) acc[l] = fmaf(dr[l], v, acc[l]);
    }
    float* op = bp + ((size_t)b * PP + k) * PP * C + c;
    #pragma unroll
    for (int l = 0; l < PP; l++) op[(size_t)l * C] = acc[l];
}

// C=64: block = (k, b), 4 waves each own a 64-wide w-segment, LDS reduce.
__global__ __launch_bounds__(256, 4) void k_fwd2_64(
        const float* __restrict__ tmp1, float* __restrict__ bp,
        const float* __restrict__ dt){
    const int C = 64;
    __shared__ float red[4 * PP * 66];   // 35.9 KB
    int k = blockIdx.x, b = blockIdx.y;
    int t = threadIdx.x;
    int c = t & 63;
    int ws = __builtin_amdgcn_readfirstlane(t >> 6);
    float acc[PP];
    #pragma unroll
    for (int l = 0; l < PP; l++) acc[l] = 0.f;
    const float* sp = tmp1 + ((size_t)b * PP + k) * S * C + c;
    for (int w = ws * 64; w < ws * 64 + 64; w++){
        float v = sp[(size_t)w * C];
        const float* dr = dt + w * KPAD;
        #pragma unroll
        for (int l = 0; l < PP; l++) acc[l] = fmaf(dr[l], v, acc[l]);
    }
    #pragma unroll
    for (int l = 0; l < PP; l++) red[(ws * PP + l) * 66 + c] = acc[l];
    __syncthreads();
    float* op = bp + ((size_t)b * PP + k) * PP * C;
    for (int e = t; e < PP * C; e += 256){
        int l = e >> 6, cc = e & 63;
        op[e] = red[(0 * PP + l) * 66 + cc] + red[(1 * PP + l) * 66 + cc]
              + red[(2 * PP + l) * 66 + cc] + red[(3 * PP + l) * 66 + cc];
    }
}

// xp[i][kl][b] = bp[b][k+i_][l+j_][c],  i = c*9 + i_*3 + j_, kl = k*32 + l
template<int C, int CC>
__global__ void k_xp_gather(const float* __restrict__ bp, float* __restrict__ xp){
    __shared__ float lds[8 * 3 * PP * (CC + 1)];
    int k  = blockIdx.x;           // 0..31
    int c0 = blockIdx.y * CC;
    int t  = threadIdx.x;
    const int TOT = 8 * 3 * PP * CC;
    for (int e = t; e < TOT; e += 256){
        int b   = e / (3 * PP * CC);
        int r   = e % (3 * PP * CC);
        int row = r / (PP * CC);
        int r2  = r % (PP * CC);
        int l   = r2 / CC;
        int c   = r2 % CC;
        lds[((b * 3 + row) * PP + l) * (CC + 1) + c] =
            bp[(((size_t)b * PP + (k + row)) * PP + l) * C + c0 + c];
    }
    __syncthreads();
    int l = t >> 3;   // 0..31
    int b = t & 7;
    for (int c = 0; c < CC; c++){
        #pragma unroll
        for (int ij = 0; ij < 9; ij++){
            int i_ = ij / 3, j_ = ij % 3;
            int i  = (c0 + c) * 9 + ij;
            float v = lds[((b * 3 + i_) * PP + (l + j_)) * (CC + 1) + c];
            xp[((size_t)i * 1024 + k * 32 + l) * 8 + b] = v;
        }
    }
}

// part[ns][b][o][kl] = sum_{i in slice ns} xp[i][kl][b] * w[i][o][kl]
template<int ITOT, int O>
__global__ void k_om(const float* __restrict__ xp, const float* __restrict__ w,
                     float* __restrict__ part){
    int bx  = blockIdx.x;
    int klt = bx & 31;
    int ot  = (bx >> 5) & 7;
    int ns  = bx >> 8;              // 0..2
    const int ILEN = ITOT / 3;
    int t  = threadIdx.x;
    int kl = klt * 32 + (t & 31);
    int o  = ot * 8 + (t >> 5);
    if (o >= O) return;
    float a0=0,a1=0,a2=0,a3=0,a4=0,a5=0,a6=0,a7=0;
    const float* xpp = xp + ((size_t)(ns * ILEN) * 1024 + kl) * 8;
    const float* wp  = w + ((size_t)(ns * ILEN) * O + o) * 1024 + kl;
    #pragma unroll 4
    for (int i = 0; i < ILEN; i++){
        float4 xa = *(const float4*)(xpp + (size_t)i * 8192);
        float4 xb = *(const float4*)(xpp + (size_t)i * 8192 + 4);
        float wv  = wp[(size_t)i * O * 1024];
        a0 = fmaf(xa.x, wv, a0); a1 = fmaf(xa.y, wv, a1);
        a2 = fmaf(xa.z, wv, a2); a3 = fmaf(xa.w, wv, a3);
        a4 = fmaf(xb.x, wv, a4); a5 = fmaf(xb.y, wv, a5);
        a6 = fmaf(xb.z, wv, a6); a7 = fmaf(xb.w, wv, a7);
    }
    float* pp = part + (size_t)ns * 8 * 64 * 1024;
    pp[((size_t)0 * 64 + o) * 1024 + kl] = a0;
    pp[((size_t)1 * 64 + o) * 1024 + kl] = a1;
    pp[((size_t)2 * 64 + o) * 1024 + kl] = a2;
    pp[((size_t)3 * 64 + o) * 1024 + kl] = a3;
    pp[((size_t)4 * 64 + o) * 1024 + kl] = a4;
    pp[((size_t)5 * 64 + o) * 1024 + kl] = a5;
    pp[((size_t)6 * 64 + o) * 1024 + kl] = a6;
    pp[((size_t)7 * 64 + o) * 1024 + kl] = a7;
}

// t2[b][k][w][o] = sum_l Dt[w][l] * om[b][o][k*32+l]; om = sum of 3 part slices
template<int O>
__global__ void k_inv1(const float* __restrict__ part, float* __restrict__ t2,
                       const float* __restrict__ dt){
    __shared__ float oms[32 * 65];
    const int N = 8 * 64 * 1024;
    int wc = blockIdx.x, k = blockIdx.y, b = blockIdx.z;
    int t = threadIdx.x;
    for (int e = t; e < 2048; e += 256){
        int o_ = e >> 5, l = e & 31;
        int idx = ((b * 64 + o_) << 10) + k * 32 + l;
        oms[l * 65 + o_] = part[idx] + part[N + idx] + part[2 * N + idx];
    }
    __syncthreads();
    int o  = t & 63;
    int wg = __builtin_amdgcn_readfirstlane(t >> 6);
    int wbase = wc * 32 + wg * 8;
    float acc[8];
    #pragma unroll
    for (int wj = 0; wj < 8; wj++) acc[wj] = 0.f;
    for (int l = 0; l < 32; l++){
        float ov = oms[l * 65 + o];
        #pragma unroll
        for (int wj = 0; wj < 8; wj++)
            acc[wj] = fmaf(dt[(wbase + wj) * KPAD + l], ov, acc[wj]);
    }
    if (o < O){
        #pragma unroll
        for (int wj = 0; wj < 8; wj++)
            t2[(((size_t)b * 32 + k) * S + wbase + wj) * 64 + o] = acc[wj];
    }
}

// MFMA k_fused, ht-loop + b128 staging + register prefetch.
// Block = (wt, b); loops ht=0..7. Each staging task owns a full 8-element
// j-run -> single b128 LDS write, lanes sweep all 32 banks (conflict-free).
// ht+1 h-tile loads issued right after the post-write barrier -> latency
// hides under MFMA+epilogue (T14); the bottom barrier's vmcnt drain is cheap.
template<bool CONV>
__global__ __launch_bounds__(256, 3) void k_fused(
        const float* __restrict__ t2, float* __restrict__ h,
        const short* __restrict__ pwh, const short* __restrict__ pwl,
        const float* __restrict__ pb,
        const short* __restrict__ dth, const short* __restrict__ dtl){
    __shared__ short t2fh[8 * 64 * 8];                 // [g=n*2+ks][l][j] 8 KB
    __shared__ short t2fl[8 * 64 * 8];
    __shared__ short hsfh[CONV ? 8 * 64 * 8 : 1];      // [g=wl*4+ks][l][j]
    __shared__ short hsfl[CONV ? 8 * 64 * 8 : 1];
    __shared__ float hres[CONV ? 64 * 64 : 1];         // [px][i] f32 16 KB
    int wt = blockIdx.x, b = blockIdx.y;
    int t = threadIdx.x;

    // ---- t2 -> B-fragments (once per block). task e: l=e&63, ks=(e>>6)&1,
    // n=e>>7; 8 strided dword loads coalesce across lanes; one b128 write.
    #pragma unroll
    for (int e2 = 0; e2 < 2; e2++){
        int e = t + e2 * 256;
        int le = e & 63, ks = (e >> 6) & 1, ne = e >> 7;
        int oe = (ne & 1) * 32 + (le & 31);
        int we = wt * 2 + (ne >> 1);
        int k0 = ks * 16 + (le >> 5) * 8;
        bfrag hv, lv;
        #pragma unroll
        for (int j = 0; j < 8; j++){
            short hi, lo;
            split_bf(t2[((size_t)(b * 32 + k0 + j) * S + we) * 64 + oe], hi, lo);
            hv[j] = hi; lv[j] = lo;
        }
        int idx = ((ne * 2 + ks) * 64 + le) * 8;
        *(bfrag*)(t2fh + idx) = hv;
        *(bfrag*)(t2fl + idx) = lv;
    }

    int l = t & 63;
    int n = t >> 6;
    int oh = n & 1, wl = n >> 1;
    int o = oh * 32 + (l & 31);

    // prefetch geometry: task A = (pxA, ihalf), task B = (pxA+32, ihalf)
    int ihalf = t & 7;
    int pxA = t >> 3;          // 0..31
    int pxB = pxA + 32;        // 32..63
    const float* hb = h + ((size_t)b * S * S + (size_t)wt * 2) * 64;
    size_t offA = ((size_t)(pxA >> 1) * S + (pxA & 1)) * 64 + ihalf * 8;
    size_t offB = ((size_t)(pxB >> 1) * S + (pxB & 1)) * 64 + ihalf * 8;
    float4 a0, a1, b0, b1;
    if (CONV){
        a0 = *(const float4*)(hb + offA);
        a1 = *(const float4*)(hb + offA + 4);
        b0 = *(const float4*)(hb + offB);
        b1 = *(const float4*)(hb + offB + 4);
    }

    for (int ht = 0; ht < 8; ht++){
        if (CONV){
            // split prefetched tile -> A-fragments (b128) + f32 residual
            int ks = ihalf >> 1;
            int lh = (ihalf & 1) * 32;
            bfrag hv, lv;
            split8(a0, a1, hv, lv);
            int idx = (((pxA & 1) * 4 + ks) * 64 + (pxA >> 1) + lh) * 8;
            *(bfrag*)(hsfh + idx) = hv;
            *(bfrag*)(hsfl + idx) = lv;
            *(float4*)(hres + pxA * 64 + ihalf * 8)     = a0;
            *(float4*)(hres + pxA * 64 + ihalf * 8 + 4) = a1;
            split8(b0, b1, hv, lv);
            idx = (((pxB & 1) * 4 + ks) * 64 + (pxB >> 1) + lh) * 8;
            *(bfrag*)(hsfh + idx) = hv;
            *(bfrag*)(hsfl + idx) = lv;
            *(float4*)(hres + pxB * 64 + ihalf * 8)     = b0;
            *(float4*)(hres + pxB * 64 + ihalf * 8 + 4) = b1;
        }
        __syncthreads();
        if (CONV && ht < 7){
            const float* hb2 = hb + (size_t)(ht + 1) * 32 * S * 64;
            a0 = *(const float4*)(hb2 + offA);
            a1 = *(const float4*)(hb2 + offA + 4);
            b0 = *(const float4*)(hb2 + offB);
            b1 = *(const float4*)(hb2 + offB + 4);
        }

        f32x16 acc = {0,0,0,0,0,0,0,0,0,0,0,0,0,0,0,0};

        // DCT matmul: A = DT rows ht*32.., B = staged t2 fragments
        int hh0 = ht * 32;
        #pragma unroll
        for (int ks = 0; ks < 2; ks++){
            int aoff = (hh0 + (l & 31)) * KPB + ks * 16 + (l >> 5) * 8;
            bfrag ah = *(const bfrag*)(dth + aoff);
            bfrag al = *(const bfrag*)(dtl + aoff);
            int boff = ((n * 2 + ks) * 64 + l) * 8;
            bfrag bh = *(const bfrag*)(t2fh + boff);
            bfrag bl = *(const bfrag*)(t2fl + boff);
            acc = __builtin_amdgcn_mfma_f32_32x32x16_bf16(ah, bh, acc, 0, 0, 0);
            acc = __builtin_amdgcn_mfma_f32_32x32x16_bf16(ah, bl, acc, 0, 0, 0);
            acc = __builtin_amdgcn_mfma_f32_32x32x16_bf16(al, bh, acc, 0, 0, 0);
        }

        if (CONV){
            #pragma unroll
            for (int ks = 0; ks < 4; ks++){
                int aoff = ((wl * 4 + ks) * 64 + l) * 8;
                bfrag ah = *(const bfrag*)(hsfh + aoff);
                bfrag al = *(const bfrag*)(hsfl + aoff);
                int boff = o * 64 + ks * 16 + (l >> 5) * 8;
                bfrag bh = *(const bfrag*)(pwh + boff);
                bfrag bl = *(const bfrag*)(pwl + boff);
                acc = __builtin_amdgcn_mfma_f32_32x32x16_bf16(ah, bh, acc, 0, 0, 0);
                acc = __builtin_amdgcn_mfma_f32_32x32x16_bf16(ah, bl, acc, 0, 0, 0);
                acc = __builtin_amdgcn_mfma_f32_32x32x16_bf16(al, bh, acc, 0, 0, 0);
            }
            float pbv = pb[o];
            #pragma unroll
            for (int r = 0; r < 16; r++){
                int row = (r & 3) + 8 * (r >> 2) + 4 * (l >> 5);
                float res = hres[(row * 2 + wl) * 64 + o];
                size_t pix = ((size_t)b * S + ht * 32 + row) * S + wt * 2 + wl;
                h[pix * 64 + o] = res + gelu_f(acc[r] + pbv);
            }
        } else {
            if (o < 61){
                #pragma unroll
                for (int r = 0; r < 16; r++){
                    int row = (r & 3) + 8 * (r >> 2) + 4 * (l >> 5);
                    size_t pix = ((size_t)b * S + ht * 32 + row) * S + wt * 2 + wl;
                    h[pix * 64 + 3 + o] = gelu_f(acc[r]);
                }
            }
        }
        __syncthreads();
    }
}

// MFMA k_mlp: P[64px][128j] = h[64px][64i] @ fc1[64i][128j]; out = gelu(P+b1)@fc2+b2.
__global__ __launch_bounds__(256, 4) void k_mlp(
        const float* __restrict__ h, const short* __restrict__ f1h,
        const short* __restrict__ f1l, const float* __restrict__ fc1b,
        const float* __restrict__ fc2w, const float* __restrict__ fc2b,
        float* __restrict__ out){
    __shared__ short ah_[2 * 4 * 64 * 8];   // [m][ks][l][j] hi, 8 KB
    __shared__ short al_[2 * 4 * 64 * 8];
    __shared__ float red[2 * 64 * 33];      // [pair][row][col], 16.9 KB
    size_t base = (size_t)blockIdx.x * 64;
    int t = threadIdx.x;
    const float* hrow = h + base * 64;
    // stage h (64px x 64i) as split-bf16 A-fragments via conflict-free b128
    #pragma unroll
    for (int e2 = 0; e2 < 2; e2++){
        int e = t + e2 * 256;
        int px = e >> 3, ih = e & 7;
        float4 v0 = *(const float4*)(hrow + px * 64 + ih * 8);
        float4 v1 = *(const float4*)(hrow + px * 64 + ih * 8 + 4);
        bfrag hv, lv;
        split8(v0, v1, hv, lv);
        int ks = ih >> 1, lh = (ih & 1) * 32, m = px >> 5;
        int idx = ((m * 4 + ks) * 64 + (px & 31) + lh) * 8;
        *(bfrag*)(ah_ + idx) = hv;
        *(bfrag*)(al_ + idx) = lv;
    }
    __syncthreads();
    int l = t & 63;
    int w = t >> 6;
    int m = w >> 1;
    int n0 = (w & 1) * 2;
    f32x16 acc0 = {0,0,0,0,0,0,0,0,0,0,0,0,0,0,0,0};
    f32x16 acc1 = {0,0,0,0,0,0,0,0,0,0,0,0,0,0,0,0};
    #pragma unroll
    for (int ks = 0; ks < 4; ks++){
        int aoff = ((m * 4 + ks) * 64 + l) * 8;
        bfrag ah = *(const bfrag*)(ah_ + aoff);
        bfrag al = *(const bfrag*)(al_ + aoff);
        int b0off = ((n0 * 4 + ks) * 64 + l) * 8;
        int b1off = (((n0 + 1) * 4 + ks) * 64 + l) * 8;
        bfrag b0h = *(const bfrag*)(f1h + b0off);
        bfrag b0l = *(const bfrag*)(f1l + b0off);
        bfrag b1h = *(const bfrag*)(f1h + b1off);
        bfrag b1l = *(const bfrag*)(f1l + b1off);
        acc0 = __builtin_amdgcn_mfma_f32_32x32x16_bf16(ah, b0h, acc0, 0, 0, 0);
        acc0 = __builtin_amdgcn_mfma_f32_32x32x16_bf16(ah, b0l, acc0, 0, 0, 0);
        acc0 = __builtin_amdgcn_mfma_f32_32x32x16_bf16(al, b0h, acc0, 0, 0, 0);
        acc1 = __builtin_amdgcn_mfma_f32_32x32x16_bf16(ah, b1h, acc1, 0, 0, 0);
        acc1 = __builtin_amdgcn_mfma_f32_32x32x16_bf16(ah, b1l, acc1, 0, 0, 0);
        acc1 = __builtin_amdgcn_mfma_f32_32x32x16_bf16(al, b1h, acc1, 0, 0, 0);
    }
    int j0 = n0 * 32 + (l & 31), j1 = j0 + 32;
    float b10 = fc1b[j0], b11 = fc1b[j1];
    float f20 = fc2w[j0], f21 = fc2w[j1];
    float* rb = red + (w & 1) * 64 * 33;
    #pragma unroll
    for (int r = 0; r < 16; r++){
        int row = (r & 3) + 8 * (r >> 2) + 4 * (l >> 5);
        rb[(m * 32 + row) * 33 + (l & 31)] =
            gelu_f(acc0[r] + b10) * f20 + gelu_f(acc1[r] + b11) * f21;
    }
    __syncthreads();
    if (t < 64){
        float s = fc2b[0];
        #pragma unroll
        for (int c = 0; c < 32; c++)
            s += red[t * 33 + c] + red[(64 + t) * 33 + c];
        out[base + t] = s;
    }
}

extern "C" void kernel_launch(void* const* d_in, const int* in_sizes, int n_in,
                              void* d_out, int out_size, void* d_ws, size_t ws_size,
                              hipStream_t stream) {
    const float* x    = (const float*)d_in[0];
    const float* wl   = (const float*)d_in[1];
    const float* wc[4] = {(const float*)d_in[2], (const float*)d_in[3],
                          (const float*)d_in[4], (const float*)d_in[5]};
    const float* pw[4] = {(const float*)d_in[6], (const float*)d_in[8],
                          (const float*)d_in[10], (const float*)d_in[12]};
    const float* pb[4] = {(const float*)d_in[7], (const float*)d_in[9],
                          (const float*)d_in[11], (const float*)d_in[13]};
    const float* fc1w = (const float*)d_in[14];
    const float* fc1b = (const float*)d_in[15];
    const float* fc2w = (const float*)d_in[16];
    const float* fc2b = (const float*)d_in[17];
    float* out = (float*)d_out;

    char* ws = (char*)d_ws;
    size_t off = 0;
    float* dt   = (float*)(ws + off); off += (size_t)S * KPAD * 4;              // 36,864
    short* dth  = (short*)(ws + off); off += (size_t)S * KPB * 2;               // 20,480
    short* dtl  = (short*)(ws + off); off += (size_t)S * KPB * 2;               // 20,480
    short* pwh  = (short*)(ws + off); off += (size_t)4 * 4096 * 2;              // 32,768
    short* pwl  = (short*)(ws + off); off += (size_t)4 * 4096 * 2;              // 32,768
    short* f1h  = (short*)(ws + off); off += (size_t)8192 * 2;                  // 16,384
    short* f1l  = (short*)(ws + off); off += (size_t)8192 * 2;                  // 16,384
    float* h    = (float*)(ws + off); off += (size_t)BB * S * S * W64 * 4;      // 134,217,728
    float* tmp1 = (float*)(ws + off); off += (size_t)BB * PP * S * W64 * 4;     // 17,825,792
    float* bp   = (float*)(ws + off); off += (size_t)BB * PP * PP * W64 * 4;    // 2,367,488
    float* xp   = (float*)(ws + off); off += (size_t)576 * 1024 * 8 * 4;        // 18,874,368
    float* part = (float*)(ws + off); off += (size_t)3 * 8 * 64 * 1024 * 4;     // 6,291,456
    float* t2   = (float*)(ws + off); off += (size_t)BB * 32 * S * W64 * 4;     // 16,777,216

    k_init_dt<<<(S * KPB + 255) / 256, 256, 0, stream>>>(dt, dth, dtl);
    for (int i = 0; i < 4; i++)
        k_prep_pw<<<16, 256, 0, stream>>>(pw[i], pwh + i * 4096, pwl + i * 4096);
    k_prep_fc1<<<32, 256, 0, stream>>>(fc1w, f1h, f1l);
    k_copy_x<<<(BB * S * S * CIN + 255) / 256, 256, 0, stream>>>(x, h);

    // ---- block 0: h[:, :, :, 3:] = gelu(pseudo_spectra(x, wl, 61)) ----
    k_fwd1<3><<<dim3(3, BB), 256, 0, stream>>>(x, tmp1, dt);
    k_fwd2_3<<<dim3(1, BB), 256, 0, stream>>>(tmp1, bp, dt);
    k_xp_gather<3, 3><<<dim3(32, 1), 256, 0, stream>>>(bp, xp);
    k_om<27, 61><<<768, 256, 0, stream>>>(xp, wl, part);
    k_inv1<61><<<dim3(8, 32, BB), 256, 0, stream>>>(part, t2, dt);
    k_fused<false><<<dim3(128, BB), 256, 0, stream>>>(
        t2, h, nullptr, nullptr, nullptr, dth, dtl);

    // ---- blocks 1..4 ----
    for (int blk = 0; blk < 4; blk++){
        k_fwd1<64><<<dim3(64, BB), 256, 0, stream>>>(h, tmp1, dt);
        k_fwd2_64<<<dim3(PP, BB), 256, 0, stream>>>(tmp1, bp, dt);
        k_xp_gather<64, 16><<<dim3(32, 4), 256, 0, stream>>>(bp, xp);
        k_om<576, 64><<<768, 256, 0, stream>>>(xp, wc[blk], part);
        k_inv1<64><<<dim3(8, 32, BB), 256, 0, stream>>>(part, t2, dt);
        k_fused<true><<<dim3(128, BB), 256, 0, stream>>>(
            t2, h, pwh + blk * 4096, pwl + blk * 4096, pb[blk], dth, dtl);
    }

    // ---- final MLP (T_fwd(T_inv2(.)) is identity for the orthonormal DCT) ----
    k_mlp<<<dim3(BB * S * S / 64), 256, 0, stream>>>(h, f1h, f1l, fc1b, fc2w, fc2b, out);
}